// Round 5
// baseline (511.403 us; speedup 1.0000x reference)
//
#include <hip/hip_runtime.h>
#include <math.h>

// TGCN: bf16 feature-space GCN aggregation (fp32 accum) -> algebraically fused
// GRU as two barrier-free MFMA GEMMs with pre-fused weights:
//   z/r: [agg|h0] @ [Wg@lgW_top ; lgW_bot],  ht: [agg|h0*r] @ [Wh@lhW_top ; lhW_bot]
// CSR-by-dst, no float atomic scatter.

#define HD 128

typedef __attribute__((ext_vector_type(8))) short short8;
typedef __attribute__((ext_vector_type(4))) float f32x4;

__device__ __forceinline__ ushort f2bf(float f) {
    union { float f; unsigned u; } v; v.f = f;
    unsigned r = (v.u + 0x7FFFu + ((v.u >> 16) & 1u)) >> 16;
    return (ushort)r;
}
__device__ __forceinline__ float bf2f(ushort h) {
    union { unsigned u; float f; } v; v.u = ((unsigned)h) << 16;
    return v.f;
}
__device__ __forceinline__ float bflo(unsigned u) {
    union { unsigned u; float f; } v; v.u = u << 16; return v.f;
}
__device__ __forceinline__ float bfhi(unsigned u) {
    union { unsigned u; float f; } v; v.u = u & 0xFFFF0000u; return v.f;
}

// nf -> bf16, h0 -> bf16 (vectorized), plus deg := 1.0 init
__global__ void prep_kernel(const float* __restrict__ nf, const float* __restrict__ h0,
                            ushort* __restrict__ nfb, ushort* __restrict__ h0b, 
                            float* deg, int n) {
    int idx = blockIdx.x * 256 + threadIdx.x;
    int total8 = n * (HD / 8);
    if (idx < total8) {
        const float4* p = (const float4*)(nf + (size_t)idx * 8);
        float4 x = p[0], y = p[1];
        short8 o;
        o[0] = (short)f2bf(x.x); o[1] = (short)f2bf(x.y);
        o[2] = (short)f2bf(x.z); o[3] = (short)f2bf(x.w);
        o[4] = (short)f2bf(y.x); o[5] = (short)f2bf(y.y);
        o[6] = (short)f2bf(y.z); o[7] = (short)f2bf(y.w);
        *(short8*)(nfb + (size_t)idx * 8) = o;
        const float4* q = (const float4*)(h0 + (size_t)idx * 8);
        float4 a = q[0], b = q[1];
        short8 o2;
        o2[0] = (short)f2bf(a.x); o2[1] = (short)f2bf(a.y);
        o2[2] = (short)f2bf(a.z); o2[3] = (short)f2bf(a.w);
        o2[4] = (short)f2bf(b.x); o2[5] = (short)f2bf(b.y);
        o2[6] = (short)f2bf(b.z); o2[7] = (short)f2bf(b.w);
        *(short8*)(h0b + (size_t)idx * 8) = o2;
    }
    if (idx < n) deg[idx] = 1.0f;
}

__global__ void edge_accum_kernel(const int* __restrict__ dst,
                                  const float* __restrict__ w,
                                  float* deg, int* counts, int E) {
    int e = blockIdx.x * blockDim.x + threadIdx.x;
    if (e < E) {
        int d = dst[e];
        atomicAdd(&deg[d], w[e]);
        atomicAdd(&counts[d], 1);
    }
}

__global__ void dinv_kernel(const float* __restrict__ deg, float* dinv, int n) {
    int i = blockIdx.x * blockDim.x + threadIdx.x;
    if (i < n) {
        float d = deg[i];
        dinv[i] = (d > 0.0f) ? rsqrtf(d) : 0.0f;
    }
}

// chunk-per-thread scan: local sum -> block scan -> local prefix writeback
__global__ __launch_bounds__(1024) void scan_kernel(const int* __restrict__ counts,
                                                    int* row_ptr, int* cursor, int n) {
    __shared__ int wsum[16];
    int tid = threadIdx.x;
    int per = (n + 1023) / 1024;
    int start = tid * per;
    int end = min(start + per, n);
    int s = 0;
    for (int i = start; i < end; ++i) s += counts[i];
    int lane = tid & 63, wid = tid >> 6;
    int x = s;
    for (int off = 1; off < 64; off <<= 1) {
        int y = __shfl_up(x, off, 64);
        if (lane >= off) x += y;
    }
    if (lane == 63) wsum[wid] = x;
    __syncthreads();
    if (wid == 0) {
        int v = (lane < 16) ? wsum[lane] : 0;
        for (int off = 1; off < 16; off <<= 1) {
            int y = __shfl_up(v, off, 64);
            if (lane >= off) v += y;
        }
        if (lane < 16) wsum[lane] = v;
    }
    __syncthreads();
    int run = x - s + ((wid == 0) ? 0 : wsum[wid - 1]);  // exclusive prefix
    for (int i = start; i < end; ++i) {
        int c = counts[i];
        row_ptr[i] = run; cursor[i] = run;
        run += c;
    }
    if (tid == 1023) row_ptr[n] = run;
}

__global__ void fill_kernel(const int* __restrict__ src, const int* __restrict__ dst,
                            const float* __restrict__ w, const float* __restrict__ dinv,
                            int* cursor, int* src_s, float* norm_s, int E) {
    int e = blockIdx.x * blockDim.x + threadIdx.x;
    if (e < E) {
        int s = src[e], d = dst[e];
        int p = atomicAdd(&cursor[d], 1);
        src_s[p] = s;
        norm_s[p] = dinv[s] * w[e] * dinv[d];
    }
}

// Fused-weight build: BT[g][j][k] (k<128: (Wg@lgW_top)[k][j], k>=128: lgW[128+k'][j]),
// lb2[g][j] = lgb[j] + sum_m bg[m]*lgW[m][j].  grid (3, 8), 256 thr.
__global__ __launch_bounds__(256) void fuse_weights_kernel(
        const float* __restrict__ Wz, const float* __restrict__ Wr,
        const float* __restrict__ Wh,
        const float* __restrict__ lzW, const float* __restrict__ lrW,
        const float* __restrict__ lhW,
        const float* __restrict__ bz, const float* __restrict__ br,
        const float* __restrict__ bh,
        const float* __restrict__ lzb, const float* __restrict__ lrb,
        const float* __restrict__ lhb,
        ushort* __restrict__ BT, float* __restrict__ lb2) {
    int g = blockIdx.x, jc = blockIdx.y;
    const float* W  = (g == 0) ? Wz  : (g == 1) ? Wr  : Wh;
    const float* lW = (g == 0) ? lzW : (g == 1) ? lrW : lhW;
    const float* bg = (g == 0) ? bz  : (g == 1) ? br  : bh;
    const float* lb = (g == 0) ? lzb : (g == 1) ? lrb : lhb;
    int t = threadIdx.x;
    int j = jc * 16 + (t & 15);
    int kg = t >> 4;   // 0..15
    float m[8] = {0, 0, 0, 0, 0, 0, 0, 0};
    for (int mm = 0; mm < 128; ++mm) {
        float lv = lW[mm * 128 + j];
#pragma unroll
        for (int u = 0; u < 8; ++u)
            m[u] += W[(kg * 8 + u) * 128 + mm] * lv;
    }
    ushort* dst = BT + ((size_t)g * 128 + j) * 256;
#pragma unroll
    for (int u = 0; u < 8; ++u) dst[kg * 8 + u] = f2bf(m[u]);
#pragma unroll
    for (int u = 0; u < 8; ++u) {
        int mm = kg * 8 + u;
        dst[128 + mm] = f2bf(lW[(128 + mm) * 128 + j]);
    }
    if (kg == 0) {
        float s = lb[j];
        for (int mm = 0; mm < 128; ++mm) s += bg[mm] * lW[mm * 128 + j];
        lb2[g * 128 + j] = s;
    }
}

// aggb[i,:] = bf16( dinv[i]^2 * nfb[i,:] + sum_e norm[e] * nfb[src[e],:] )
__global__ __launch_bounds__(256) void agg_feat_kernel(
        const unsigned* __restrict__ nfb32, const float* __restrict__ dinv,
        const int* __restrict__ row_ptr, const int* __restrict__ src_s,
        const float* __restrict__ norm_s, unsigned* __restrict__ aggb32, int n) {
    int t = threadIdx.x & 63;            // column pair
    int grp = threadIdx.x >> 6;
    int i = blockIdx.x * 4 + grp;
    if (i >= n) return;
    float di = dinv[i];
    unsigned uself = nfb32[(size_t)i * 64 + t];
    float a0 = di * di * bflo(uself);
    float a1 = di * di * bfhi(uself);
    int e0 = row_ptr[i], e1 = row_ptr[i + 1];
    for (int e = e0; e < e1; e += 8) {
        unsigned v[8]; float w[8];
#pragma unroll
        for (int u = 0; u < 8; ++u) {
            int ee = e + u;
            bool ok = ee < e1;
            int s = ok ? src_s[ee] : src_s[e0];
            w[u] = ok ? norm_s[ee] : 0.0f;
            v[u] = nfb32[(size_t)s * 64 + t];
        }
#pragma unroll
        for (int u = 0; u < 8; ++u) {
            a0 += w[u] * bflo(v[u]);
            a1 += w[u] * bfhi(v[u]);
        }
    }
    aggb32[(size_t)i * 64 + t] = (unsigned)f2bf(a0) | ((unsigned)f2bf(a1) << 16);
}

// z/r GEMM: acc = [aggb | h0b] @ BT_g  (K=256), barrier-free, A-frags from global.
// g=0: zsb = sigmoid(acc+lb2);  g=1: hqb = sigmoid(acc+lb2) * h0
__global__ __launch_bounds__(256) void gemm_zr_kernel(
        const ushort* __restrict__ aggb, const ushort* __restrict__ h0b,
        const ushort* __restrict__ BT, const float* __restrict__ lb2,
        ushort* __restrict__ zsb, ushort* __restrict__ hqb, int NP) {
    int w = threadIdx.x >> 6, lane = threadIdx.x & 63;
    int g = blockIdx.y;
    size_t row0 = (size_t)blockIdx.x * 128 + w * 32;
    int rlo = lane & 15, koff = (lane >> 4) * 8, rbase = (lane >> 4) * 4;
    const ushort* B = BT + (size_t)g * 128 * 256;
    f32x4 acc[2][8];
    const f32x4 zero4 = {0.f, 0.f, 0.f, 0.f};
#pragma unroll
    for (int rf = 0; rf < 2; ++rf)
#pragma unroll
        for (int cf = 0; cf < 8; ++cf) acc[rf][cf] = zero4;
    const ushort* A0 = aggb + (row0 + rlo) * HD;
    const ushort* A1 = aggb + (row0 + 16 + rlo) * HD;
    const ushort* H0 = h0b + (row0 + rlo) * HD;
    const ushort* H1 = h0b + (row0 + 16 + rlo) * HD;
#pragma unroll
    for (int ks = 0; ks < 8; ++ks) {
        const ushort* pa0 = (ks < 4) ? A0 + ks * 32 + koff : H0 + (ks - 4) * 32 + koff;
        const ushort* pa1 = (ks < 4) ? A1 + ks * 32 + koff : H1 + (ks - 4) * 32 + koff;
        short8 af0 = *(const short8*)pa0;
        short8 af1 = *(const short8*)pa1;
#pragma unroll
        for (int cf = 0; cf < 8; ++cf) {
            short8 bf = *(const short8*)(B + (size_t)(cf * 16 + rlo) * 256 + ks * 32 + koff);
            acc[0][cf] = __builtin_amdgcn_mfma_f32_16x16x32_bf16(af0, bf, acc[0][cf], 0, 0, 0);
            acc[1][cf] = __builtin_amdgcn_mfma_f32_16x16x32_bf16(af1, bf, acc[1][cf], 0, 0, 0);
        }
    }
#pragma unroll
    for (int cf = 0; cf < 8; ++cf) {
        int lc = cf * 16 + rlo;
        float bv = lb2[g * 128 + lc];
#pragma unroll
        for (int rf = 0; rf < 2; ++rf)
#pragma unroll
            for (int i = 0; i < 4; ++i) {
                size_t row = row0 + rf * 16 + rbase + i;
                float s = 1.0f / (1.0f + expf(-(acc[rf][cf][i] + bv)));
                if (g == 0) {
                    zsb[row * HD + lc] = f2bf(s);
                } else {
                    float hv = bf2f(h0b[row * HD + lc]);
                    hqb[row * HD + lc] = f2bf(s * hv);
                }
            }
    }
}

// ht GEMM: acc = [aggb | hqb] @ BT_h (K=256); h_new = z*h0 + (1-z)*tanh(acc+lb2)
__global__ __launch_bounds__(256) void gemm_ht_kernel(
        const ushort* __restrict__ aggb, const ushort* __restrict__ hqb,
        const ushort* __restrict__ h0b, const ushort* __restrict__ zsb,
        const ushort* __restrict__ BT, const float* __restrict__ lb2,
        float* __restrict__ hout, int n) {
    int w = threadIdx.x >> 6, lane = threadIdx.x & 63;
    size_t row0 = (size_t)blockIdx.x * 128 + w * 32;
    int rlo = lane & 15, koff = (lane >> 4) * 8, rbase = (lane >> 4) * 4;
    const ushort* B = BT + (size_t)2 * 128 * 256;
    f32x4 acc[2][8];
    const f32x4 zero4 = {0.f, 0.f, 0.f, 0.f};
#pragma unroll
    for (int rf = 0; rf < 2; ++rf)
#pragma unroll
        for (int cf = 0; cf < 8; ++cf) acc[rf][cf] = zero4;
    const ushort* A0 = aggb + (row0 + rlo) * HD;
    const ushort* A1 = aggb + (row0 + 16 + rlo) * HD;
    const ushort* H0 = hqb + (row0 + rlo) * HD;
    const ushort* H1 = hqb + (row0 + 16 + rlo) * HD;
#pragma unroll
    for (int ks = 0; ks < 8; ++ks) {
        const ushort* pa0 = (ks < 4) ? A0 + ks * 32 + koff : H0 + (ks - 4) * 32 + koff;
        const ushort* pa1 = (ks < 4) ? A1 + ks * 32 + koff : H1 + (ks - 4) * 32 + koff;
        short8 af0 = *(const short8*)pa0;
        short8 af1 = *(const short8*)pa1;
#pragma unroll
        for (int cf = 0; cf < 8; ++cf) {
            short8 bf = *(const short8*)(B + (size_t)(cf * 16 + rlo) * 256 + ks * 32 + koff);
            acc[0][cf] = __builtin_amdgcn_mfma_f32_16x16x32_bf16(af0, bf, acc[0][cf], 0, 0, 0);
            acc[1][cf] = __builtin_amdgcn_mfma_f32_16x16x32_bf16(af1, bf, acc[1][cf], 0, 0, 0);
        }
    }
#pragma unroll
    for (int cf = 0; cf < 8; ++cf) {
        int lc = cf * 16 + rlo;
        float bv = lb2[2 * 128 + lc];
#pragma unroll
        for (int rf = 0; rf < 2; ++rf)
#pragma unroll
            for (int i = 0; i < 4; ++i) {
                size_t row = row0 + rf * 16 + rbase + i;
                if (row < (size_t)n) {
                    float ht = tanhf(acc[rf][cf][i] + bv);
                    float z = bf2f(zsb[row * HD + lc]);
                    float h0v = bf2f(h0b[row * HD + lc]);
                    hout[row * HD + lc] = z * h0v + (1.0f - z) * ht;
                }
            }
    }
}

__global__ __launch_bounds__(128) void pool_kernel(
        const float* __restrict__ hout, const int* __restrict__ nids,
        float* pooled, int U) {
    int t = threadIdx.x;
    float pa = 0.0f;
    for (int u = blockIdx.x; u < U; u += gridDim.x) {
        int nid = nids[u];
        pa += fmaxf(hout[(size_t)nid * HD + t], 0.0f);
    }
    atomicAdd(&pooled[t], pa);
}

__global__ __launch_bounds__(128) void decoder_kernel(
        const float* __restrict__ pooled, float invU,
        const float* __restrict__ linW, const float* __restrict__ linb,
        const float* __restrict__ dnW, const float* __restrict__ dnb,
        const float* __restrict__ outW, const float* __restrict__ outb,
        float* pred, int C) {
    __shared__ float sh[HD];
    int t = threadIdx.x;
    sh[t] = pooled[t] * invU;
    __syncthreads();
    float v = linb[t];
    for (int k = 0; k < HD; ++k) v += sh[k] * linW[k * HD + t];
    __syncthreads();
    sh[t] = v;
    __syncthreads();
    float d = dnb[t];
    for (int k = 0; k < HD; ++k) d += sh[k] * dnW[k * HD + t];
    d = fmaxf(d, 0.0f);
    __syncthreads();
    sh[t] = d;
    __syncthreads();
    if (t < C) {
        float p = outb[t];
        for (int k = 0; k < HD; ++k) p += sh[k] * outW[k * C + t];
        pred[t] = 1.0f / (1.0f + expf(-p));
    }
}

extern "C" void kernel_launch(void* const* d_in, const int* in_sizes, int n_in,
                              void* d_out, int out_size, void* d_ws, size_t ws_size,
                              hipStream_t stream) {
    const float* node_feat = (const float*)d_in[0];
    const float* edge_w    = (const float*)d_in[1];
    const float* h0        = (const float*)d_in[2];
    const float* Wz  = (const float*)d_in[3];  const float* bz  = (const float*)d_in[4];
    const float* Wr  = (const float*)d_in[5];  const float* br  = (const float*)d_in[6];
    const float* Wh  = (const float*)d_in[7];  const float* bh  = (const float*)d_in[8];
    const float* lzW = (const float*)d_in[9];  const float* lzb = (const float*)d_in[10];
    const float* lrW = (const float*)d_in[11]; const float* lrb = (const float*)d_in[12];
    const float* lhW = (const float*)d_in[13]; const float* lhb = (const float*)d_in[14];
    const float* linW= (const float*)d_in[15]; const float* linb= (const float*)d_in[16];
    const float* dnW = (const float*)d_in[17]; const float* dnb = (const float*)d_in[18];
    const float* outW= (const float*)d_in[19]; const float* outb= (const float*)d_in[20];
    const int* src  = (const int*)d_in[21];
    const int* dst  = (const int*)d_in[22];
    const int* nids = (const int*)d_in[23];

    const int N = in_sizes[2] / HD;
    const int E = in_sizes[1];
    const int U = in_sizes[23];
    const int C = in_sizes[20];
    const int NP = (N + 127) & ~127;   // row-padded for 128-row GEMM tiles

    float* out  = (float*)d_out;
    float* pred = out;          // [C]
    float* hout = out + C;      // [N,H]

    // workspace layout (16B-aligned chunks); zsb aliases nfb (dead after agg_feat)
    char* p = (char*)d_ws;
    auto alloc = [&](size_t bytes) { char* r = p; p += (bytes + 15) & ~(size_t)15; return r; };
    float* deg    = (float*)alloc((size_t)N * 4);
    float* dinv   = (float*)alloc((size_t)N * 4);
    float* norm_s = (float*)alloc((size_t)E * 4);
    float* pooled = (float*)alloc(HD * 4);
    int*   counts = (int*)alloc((size_t)N * 4);
    int*   row_ptr= (int*)alloc((size_t)(N + 1) * 4);
    int*   cursor = (int*)alloc((size_t)N * 4);
    int*   src_s  = (int*)alloc((size_t)E * 4);
    ushort* nfb   = (ushort*)alloc((size_t)NP * HD * 2);  // -> zsb after agg
    ushort* aggb  = (ushort*)alloc((size_t)NP * HD * 2);
    ushort* h0b   = (ushort*)alloc((size_t)NP * HD * 2);
    ushort* hqb   = (ushort*)alloc((size_t)NP * HD * 2);
    ushort* BT    = (ushort*)alloc((size_t)3 * 128 * 256 * 2);
    float* lb2    = (float*)alloc(384 * 4);
    ushort* zsb   = nfb;  // alias

    hipMemsetAsync(counts, 0, (size_t)N * sizeof(int), stream);
    hipMemsetAsync(pooled, 0, HD * sizeof(float), stream);

    int prep_items = N * (HD / 8);
    prep_kernel<<<(prep_items + 255) / 256, 256, 0, stream>>>(node_feat, h0, nfb, h0b, deg, N);
    edge_accum_kernel<<<(E + 255) / 256, 256, 0, stream>>>(dst, edge_w, deg, counts, E);
    dinv_kernel<<<(N + 255) / 256, 256, 0, stream>>>(deg, dinv, N);
    scan_kernel<<<1, 1024, 0, stream>>>(counts, row_ptr, cursor, N);
    fill_kernel<<<(E + 255) / 256, 256, 0, stream>>>(src, dst, edge_w, dinv, cursor,
                                                     src_s, norm_s, E);
    dim3 fg(3, 8);
    fuse_weights_kernel<<<fg, 256, 0, stream>>>(Wz, Wr, Wh, lzW, lrW, lhW,
                                                bz, br, bh, lzb, lrb, lhb, BT, lb2);
    agg_feat_kernel<<<(N + 3) / 4, 256, 0, stream>>>(
        (const unsigned*)nfb, dinv, row_ptr, src_s, norm_s, (unsigned*)aggb, N);
    dim3 zg(NP / 128, 2);
    gemm_zr_kernel<<<zg, 256, 0, stream>>>(aggb, h0b, BT, lb2, zsb, hqb, NP);
    gemm_ht_kernel<<<NP / 128, 256, 0, stream>>>(aggb, hqb, h0b, zsb, BT, lb2, hout, N);
    pool_kernel<<<512, 128, 0, stream>>>(hout, nids, pooled, U);
    decoder_kernel<<<1, 128, 0, stream>>>(pooled, 1.0f / (float)U,
                                          linW, linb, dnW, dnb, outW, outb, pred, C);
}

// Round 6
// 399.399 us; speedup vs baseline: 1.2804x; 1.2804x over previous
//
#include <hip/hip_runtime.h>
#include <math.h>

// TGCN: bf16 feature-space GCN aggregation (fp32 accum) -> algebraically fused
// GRU as two barrier-free MFMA GEMMs with pre-fused weights:
//   z/r: [agg|h0] @ [Wg@lgW_top ; lgW_bot],  ht: [agg|h0*r] @ [Wh@lhW_top ; lhW_bot]
// CSR-by-dst via hierarchical 3-kernel scan. No float atomic scatter.

#define HD 128

typedef __attribute__((ext_vector_type(8))) short short8;
typedef __attribute__((ext_vector_type(4))) float f32x4;

__device__ __forceinline__ ushort f2bf(float f) {
    union { float f; unsigned u; } v; v.f = f;
    unsigned r = (v.u + 0x7FFFu + ((v.u >> 16) & 1u)) >> 16;
    return (ushort)r;
}
__device__ __forceinline__ float bf2f(ushort h) {
    union { unsigned u; float f; } v; v.u = ((unsigned)h) << 16;
    return v.f;
}
__device__ __forceinline__ float bflo(unsigned u) {
    union { unsigned u; float f; } v; v.u = u << 16; return v.f;
}
__device__ __forceinline__ float bfhi(unsigned u) {
    union { unsigned u; float f; } v; v.u = u & 0xFFFF0000u; return v.f;
}

// nf -> bf16, h0 -> bf16 (vectorized), plus deg := 1.0 init
__global__ void prep_kernel(const float* __restrict__ nf, const float* __restrict__ h0,
                            ushort* __restrict__ nfb, ushort* __restrict__ h0b,
                            float* deg, int n) {
    int idx = blockIdx.x * 256 + threadIdx.x;
    int total8 = n * (HD / 8);
    if (idx < total8) {
        const float4* p = (const float4*)(nf + (size_t)idx * 8);
        float4 x = p[0], y = p[1];
        short8 o;
        o[0] = (short)f2bf(x.x); o[1] = (short)f2bf(x.y);
        o[2] = (short)f2bf(x.z); o[3] = (short)f2bf(x.w);
        o[4] = (short)f2bf(y.x); o[5] = (short)f2bf(y.y);
        o[6] = (short)f2bf(y.z); o[7] = (short)f2bf(y.w);
        *(short8*)(nfb + (size_t)idx * 8) = o;
        const float4* q = (const float4*)(h0 + (size_t)idx * 8);
        float4 a = q[0], b = q[1];
        short8 o2;
        o2[0] = (short)f2bf(a.x); o2[1] = (short)f2bf(a.y);
        o2[2] = (short)f2bf(a.z); o2[3] = (short)f2bf(a.w);
        o2[4] = (short)f2bf(b.x); o2[5] = (short)f2bf(b.y);
        o2[6] = (short)f2bf(b.z); o2[7] = (short)f2bf(b.w);
        *(short8*)(h0b + (size_t)idx * 8) = o2;
    }
    if (idx < n) deg[idx] = 1.0f;
}

__global__ void edge_accum_kernel(const int* __restrict__ dst,
                                  const float* __restrict__ w,
                                  float* deg, int* counts, int E) {
    int e = blockIdx.x * blockDim.x + threadIdx.x;
    if (e < E) {
        int d = dst[e];
        atomicAdd(&deg[d], w[e]);
        atomicAdd(&counts[d], 1);
    }
}

__global__ void dinv_kernel(const float* __restrict__ deg, float* dinv, int n) {
    int i = blockIdx.x * blockDim.x + threadIdx.x;
    if (i < n) {
        float d = deg[i];
        dinv[i] = (d > 0.0f) ? rsqrtf(d) : 0.0f;
    }
}

// ---- hierarchical scan: partial sums (1024 elems / 256-thr block) ----
__global__ __launch_bounds__(256) void scan_partial_kernel(
        const int* __restrict__ counts, int* __restrict__ bsums, int n) {
    __shared__ int ws[4];
    int b = blockIdx.x, t = threadIdx.x;
    int idx = b * 1024 + t * 4;
    int4 v = {0, 0, 0, 0};
    if (idx + 3 < n) v = *(const int4*)(counts + idx);
    else {
        if (idx < n) v.x = counts[idx];
        if (idx + 1 < n) v.y = counts[idx + 1];
        if (idx + 2 < n) v.z = counts[idx + 2];
        if (idx + 3 < n) v.w = counts[idx + 3];
    }
    int s = v.x + v.y + v.z + v.w;
    for (int off = 1; off < 64; off <<= 1) s += __shfl_xor(s, off, 64);
    if ((t & 63) == 0) ws[t >> 6] = s;
    __syncthreads();
    if (t == 0) bsums[b] = ws[0] + ws[1] + ws[2] + ws[3];
}

// single-wave-style scan of nb (<=1024) block sums -> exclusive; writes row_ptr[n]
__global__ __launch_bounds__(1024) void scan_bsums_kernel(
        int* __restrict__ bsums, int* __restrict__ rp_total, int nb) {
    __shared__ int ws[16];
    int t = threadIdx.x;
    int v = (t < nb) ? bsums[t] : 0;
    int lane = t & 63, wid = t >> 6;
    int x = v;
    for (int off = 1; off < 64; off <<= 1) {
        int y = __shfl_up(x, off, 64);
        if (lane >= off) x += y;
    }
    if (lane == 63) ws[wid] = x;
    __syncthreads();
    if (wid == 0) {
        int s = (lane < 16) ? ws[lane] : 0;
        for (int off = 1; off < 16; off <<= 1) {
            int y = __shfl_up(s, off, 64);
            if (lane >= off) s += y;
        }
        if (lane < 16) ws[lane] = s;
    }
    __syncthreads();
    int excl = x - v + ((wid == 0) ? 0 : ws[wid - 1]);
    if (t < nb) bsums[t] = excl;
    if (t == nb - 1) *rp_total = excl + v;
}

// final: per-block local scan + block offset -> row_ptr, cursor
__global__ __launch_bounds__(256) void scan_final_kernel(
        const int* __restrict__ counts, const int* __restrict__ bsums,
        int* __restrict__ row_ptr, int* __restrict__ cursor, int n) {
    __shared__ int ws[4];
    int b = blockIdx.x, t = threadIdx.x;
    int idx = b * 1024 + t * 4;
    int4 v = {0, 0, 0, 0};
    if (idx + 3 < n) v = *(const int4*)(counts + idx);
    else {
        if (idx < n) v.x = counts[idx];
        if (idx + 1 < n) v.y = counts[idx + 1];
        if (idx + 2 < n) v.z = counts[idx + 2];
        if (idx + 3 < n) v.w = counts[idx + 3];
    }
    int s = v.x + v.y + v.z + v.w;
    int lane = t & 63, wid = t >> 6;
    int x = s;
    for (int off = 1; off < 64; off <<= 1) {
        int y = __shfl_up(x, off, 64);
        if (lane >= off) x += y;
    }
    if (lane == 63) ws[wid] = x;
    __syncthreads();
    int woff = 0;
    for (int wv = 0; wv < wid; ++wv) woff += ws[wv];
    int run = bsums[b] + woff + x - s;
    int4 rp;
    rp.x = run; rp.y = run + v.x; rp.z = rp.y + v.y; rp.w = rp.z + v.z;
    if (idx + 3 < n) {
        *(int4*)(row_ptr + idx) = rp;
        *(int4*)(cursor + idx) = rp;
    } else {
        if (idx < n) { row_ptr[idx] = rp.x; cursor[idx] = rp.x; }
        if (idx + 1 < n) { row_ptr[idx + 1] = rp.y; cursor[idx + 1] = rp.y; }
        if (idx + 2 < n) { row_ptr[idx + 2] = rp.z; cursor[idx + 2] = rp.z; }
        if (idx + 3 < n) { row_ptr[idx + 3] = rp.w; cursor[idx + 3] = rp.w; }
    }
}

__global__ void fill_kernel(const int* __restrict__ src, const int* __restrict__ dst,
                            const float* __restrict__ w, const float* __restrict__ dinv,
                            int* cursor, int* src_s, float* norm_s, int E) {
    int e = blockIdx.x * blockDim.x + threadIdx.x;
    if (e < E) {
        int s = src[e], d = dst[e];
        int p = atomicAdd(&cursor[d], 1);
        src_s[p] = s;
        norm_s[p] = dinv[s] * w[e] * dinv[d];
    }
}

// Fused-weight build, parallel+coalesced. grid (3,16), 256 thr.
// Block (g,kt): M[k0..k0+8)[0..128) where M = Wg @ lgW_top; also copies 8 rows
// of lgW_bot. BT[g][j][k]: k<128 -> M[k][j], k>=128 -> lgW[128+k'][j].
__global__ __launch_bounds__(256) void fuse_weights_kernel(
        const float* __restrict__ Wz, const float* __restrict__ Wr,
        const float* __restrict__ Wh,
        const float* __restrict__ lzW, const float* __restrict__ lrW,
        const float* __restrict__ lhW,
        ushort* __restrict__ BT) {
    int g = blockIdx.x, kt = blockIdx.y;
    const float* W  = (g == 0) ? Wz  : (g == 1) ? Wr  : Wh;
    const float* lW = (g == 0) ? lzW : (g == 1) ? lrW : lhW;
    int t = threadIdx.x;
    int j = t & 127, kh = t >> 7;          // kh in {0,1}
    int k0 = kt * 8 + kh * 4;
    float m0 = 0.f, m1 = 0.f, m2 = 0.f, m3 = 0.f;
    for (int mm = 0; mm < 128; ++mm) {
        float lv = lW[mm * 128 + j];       // coalesced across j
        m0 += W[(k0 + 0) * 128 + mm] * lv; // wave-uniform -> broadcast
        m1 += W[(k0 + 1) * 128 + mm] * lv;
        m2 += W[(k0 + 2) * 128 + mm] * lv;
        m3 += W[(k0 + 3) * 128 + mm] * lv;
    }
    ushort* dstc = BT + ((size_t)g * 128 + j) * 256;
    dstc[k0 + 0] = f2bf(m0); dstc[k0 + 1] = f2bf(m1);
    dstc[k0 + 2] = f2bf(m2); dstc[k0 + 3] = f2bf(m3);
#pragma unroll
    for (int u = 0; u < 4; ++u) {
        int mm = k0 + u;
        dstc[128 + mm] = f2bf(lW[(128 + mm) * 128 + j]);
    }
}

// lb2[g][j] = lgb[j] + sum_m bg[m]*lgW_top[m][j]
__global__ __launch_bounds__(128) void lb2_kernel(
        const float* __restrict__ lzW, const float* __restrict__ lrW,
        const float* __restrict__ lhW,
        const float* __restrict__ bz, const float* __restrict__ br,
        const float* __restrict__ bh,
        const float* __restrict__ lzb, const float* __restrict__ lrb,
        const float* __restrict__ lhb,
        float* __restrict__ lb2) {
    int g = blockIdx.x, j = threadIdx.x;
    const float* lW = (g == 0) ? lzW : (g == 1) ? lrW : lhW;
    const float* bg = (g == 0) ? bz  : (g == 1) ? br  : bh;
    const float* lb = (g == 0) ? lzb : (g == 1) ? lrb : lhb;
    float s = lb[j];
    for (int mm = 0; mm < 128; ++mm) s += bg[mm] * lW[mm * 128 + j];
    lb2[g * 128 + j] = s;
}

// aggb[i,:] = bf16( dinv[i]^2 * nfb[i,:] + sum_e norm[e] * nfb[src[e],:] )
__global__ __launch_bounds__(256) void agg_feat_kernel(
        const unsigned* __restrict__ nfb32, const float* __restrict__ dinv,
        const int* __restrict__ row_ptr, const int* __restrict__ src_s,
        const float* __restrict__ norm_s, unsigned* __restrict__ aggb32, int n) {
    int t = threadIdx.x & 63;            // column pair
    int grp = threadIdx.x >> 6;
    int i = blockIdx.x * 4 + grp;
    if (i >= n) return;
    float di = dinv[i];
    unsigned uself = nfb32[(size_t)i * 64 + t];
    float a0 = di * di * bflo(uself);
    float a1 = di * di * bfhi(uself);
    int e0 = row_ptr[i], e1 = row_ptr[i + 1];
    for (int e = e0; e < e1; e += 8) {
        unsigned v[8]; float w[8];
#pragma unroll
        for (int u = 0; u < 8; ++u) {
            int ee = e + u;
            bool ok = ee < e1;
            int s = ok ? src_s[ee] : src_s[e0];
            w[u] = ok ? norm_s[ee] : 0.0f;
            v[u] = nfb32[(size_t)s * 64 + t];
        }
#pragma unroll
        for (int u = 0; u < 8; ++u) {
            a0 += w[u] * bflo(v[u]);
            a1 += w[u] * bfhi(v[u]);
        }
    }
    aggb32[(size_t)i * 64 + t] = (unsigned)f2bf(a0) | ((unsigned)f2bf(a1) << 16);
}

// z/r GEMM: acc = [aggb | h0b] @ BT_g  (K=256), barrier-free, A-frags from global.
// g=0: zsb = sigmoid(acc+lb2);  g=1: hqb = sigmoid(acc+lb2) * h0
__global__ __launch_bounds__(256) void gemm_zr_kernel(
        const ushort* __restrict__ aggb, const ushort* __restrict__ h0b,
        const ushort* __restrict__ BT, const float* __restrict__ lb2,
        ushort* __restrict__ zsb, ushort* __restrict__ hqb, int NP) {
    int w = threadIdx.x >> 6, lane = threadIdx.x & 63;
    int g = blockIdx.y;
    size_t row0 = (size_t)blockIdx.x * 128 + w * 32;
    int rlo = lane & 15, koff = (lane >> 4) * 8, rbase = (lane >> 4) * 4;
    const ushort* B = BT + (size_t)g * 128 * 256;
    f32x4 acc[2][8];
    const f32x4 zero4 = {0.f, 0.f, 0.f, 0.f};
#pragma unroll
    for (int rf = 0; rf < 2; ++rf)
#pragma unroll
        for (int cf = 0; cf < 8; ++cf) acc[rf][cf] = zero4;
    const ushort* A0 = aggb + (row0 + rlo) * HD;
    const ushort* A1 = aggb + (row0 + 16 + rlo) * HD;
    const ushort* H0 = h0b + (row0 + rlo) * HD;
    const ushort* H1 = h0b + (row0 + 16 + rlo) * HD;
#pragma unroll
    for (int ks = 0; ks < 8; ++ks) {
        const ushort* pa0 = (ks < 4) ? A0 + ks * 32 + koff : H0 + (ks - 4) * 32 + koff;
        const ushort* pa1 = (ks < 4) ? A1 + ks * 32 + koff : H1 + (ks - 4) * 32 + koff;
        short8 af0 = *(const short8*)pa0;
        short8 af1 = *(const short8*)pa1;
#pragma unroll
        for (int cf = 0; cf < 8; ++cf) {
            short8 bf = *(const short8*)(B + (size_t)(cf * 16 + rlo) * 256 + ks * 32 + koff);
            acc[0][cf] = __builtin_amdgcn_mfma_f32_16x16x32_bf16(af0, bf, acc[0][cf], 0, 0, 0);
            acc[1][cf] = __builtin_amdgcn_mfma_f32_16x16x32_bf16(af1, bf, acc[1][cf], 0, 0, 0);
        }
    }
#pragma unroll
    for (int cf = 0; cf < 8; ++cf) {
        int lc = cf * 16 + rlo;
        float bv = lb2[g * 128 + lc];
#pragma unroll
        for (int rf = 0; rf < 2; ++rf)
#pragma unroll
            for (int i = 0; i < 4; ++i) {
                size_t row = row0 + rf * 16 + rbase + i;
                float s = 1.0f / (1.0f + expf(-(acc[rf][cf][i] + bv)));
                if (g == 0) {
                    zsb[row * HD + lc] = f2bf(s);
                } else {
                    float hv = bf2f(h0b[row * HD + lc]);
                    hqb[row * HD + lc] = f2bf(s * hv);
                }
            }
    }
}

// ht GEMM: acc = [aggb | hqb] @ BT_h (K=256); h_new = z*h0 + (1-z)*tanh(acc+lb2)
__global__ __launch_bounds__(256) void gemm_ht_kernel(
        const ushort* __restrict__ aggb, const ushort* __restrict__ hqb,
        const ushort* __restrict__ h0b, const ushort* __restrict__ zsb,
        const ushort* __restrict__ BT, const float* __restrict__ lb2,
        float* __restrict__ hout, int n) {
    int w = threadIdx.x >> 6, lane = threadIdx.x & 63;
    size_t row0 = (size_t)blockIdx.x * 128 + w * 32;
    int rlo = lane & 15, koff = (lane >> 4) * 8, rbase = (lane >> 4) * 4;
    const ushort* B = BT + (size_t)2 * 128 * 256;
    f32x4 acc[2][8];
    const f32x4 zero4 = {0.f, 0.f, 0.f, 0.f};
#pragma unroll
    for (int rf = 0; rf < 2; ++rf)
#pragma unroll
        for (int cf = 0; cf < 8; ++cf) acc[rf][cf] = zero4;
    const ushort* A0 = aggb + (row0 + rlo) * HD;
    const ushort* A1 = aggb + (row0 + 16 + rlo) * HD;
    const ushort* H0 = hqb + (row0 + rlo) * HD;
    const ushort* H1 = hqb + (row0 + 16 + rlo) * HD;
#pragma unroll
    for (int ks = 0; ks < 8; ++ks) {
        const ushort* pa0 = (ks < 4) ? A0 + ks * 32 + koff : H0 + (ks - 4) * 32 + koff;
        const ushort* pa1 = (ks < 4) ? A1 + ks * 32 + koff : H1 + (ks - 4) * 32 + koff;
        short8 af0 = *(const short8*)pa0;
        short8 af1 = *(const short8*)pa1;
#pragma unroll
        for (int cf = 0; cf < 8; ++cf) {
            short8 bf = *(const short8*)(B + (size_t)(cf * 16 + rlo) * 256 + ks * 32 + koff);
            acc[0][cf] = __builtin_amdgcn_mfma_f32_16x16x32_bf16(af0, bf, acc[0][cf], 0, 0, 0);
            acc[1][cf] = __builtin_amdgcn_mfma_f32_16x16x32_bf16(af1, bf, acc[1][cf], 0, 0, 0);
        }
    }
#pragma unroll
    for (int cf = 0; cf < 8; ++cf) {
        int lc = cf * 16 + rlo;
        float bv = lb2[2 * 128 + lc];
#pragma unroll
        for (int rf = 0; rf < 2; ++rf)
#pragma unroll
            for (int i = 0; i < 4; ++i) {
                size_t row = row0 + rf * 16 + rbase + i;
                if (row < (size_t)n) {
                    float ht = tanhf(acc[rf][cf][i] + bv);
                    float z = bf2f(zsb[row * HD + lc]);
                    float h0v = bf2f(h0b[row * HD + lc]);
                    hout[row * HD + lc] = z * h0v + (1.0f - z) * ht;
                }
            }
    }
}

__global__ __launch_bounds__(128) void pool_kernel(
        const float* __restrict__ hout, const int* __restrict__ nids,
        float* pooled, int U) {
    int t = threadIdx.x;
    float pa = 0.0f;
    for (int u = blockIdx.x; u < U; u += gridDim.x) {
        int nid = nids[u];
        pa += fmaxf(hout[(size_t)nid * HD + t], 0.0f);
    }
    atomicAdd(&pooled[t], pa);
}

__global__ __launch_bounds__(128) void decoder_kernel(
        const float* __restrict__ pooled, float invU,
        const float* __restrict__ linW, const float* __restrict__ linb,
        const float* __restrict__ dnW, const float* __restrict__ dnb,
        const float* __restrict__ outW, const float* __restrict__ outb,
        float* pred, int C) {
    __shared__ float sh[HD];
    int t = threadIdx.x;
    sh[t] = pooled[t] * invU;
    __syncthreads();
    float v = linb[t];
    for (int k = 0; k < HD; ++k) v += sh[k] * linW[k * HD + t];
    __syncthreads();
    sh[t] = v;
    __syncthreads();
    float d = dnb[t];
    for (int k = 0; k < HD; ++k) d += sh[k] * dnW[k * HD + t];
    d = fmaxf(d, 0.0f);
    __syncthreads();
    sh[t] = d;
    __syncthreads();
    if (t < C) {
        float p = outb[t];
        for (int k = 0; k < HD; ++k) p += sh[k] * outW[k * C + t];
        pred[t] = 1.0f / (1.0f + expf(-p));
    }
}

extern "C" void kernel_launch(void* const* d_in, const int* in_sizes, int n_in,
                              void* d_out, int out_size, void* d_ws, size_t ws_size,
                              hipStream_t stream) {
    const float* node_feat = (const float*)d_in[0];
    const float* edge_w    = (const float*)d_in[1];
    const float* h0        = (const float*)d_in[2];
    const float* Wz  = (const float*)d_in[3];  const float* bz  = (const float*)d_in[4];
    const float* Wr  = (const float*)d_in[5];  const float* br  = (const float*)d_in[6];
    const float* Wh  = (const float*)d_in[7];  const float* bh  = (const float*)d_in[8];
    const float* lzW = (const float*)d_in[9];  const float* lzb = (const float*)d_in[10];
    const float* lrW = (const float*)d_in[11]; const float* lrb = (const float*)d_in[12];
    const float* lhW = (const float*)d_in[13]; const float* lhb = (const float*)d_in[14];
    const float* linW= (const float*)d_in[15]; const float* linb= (const float*)d_in[16];
    const float* dnW = (const float*)d_in[17]; const float* dnb = (const float*)d_in[18];
    const float* outW= (const float*)d_in[19]; const float* outb= (const float*)d_in[20];
    const int* src  = (const int*)d_in[21];
    const int* dst  = (const int*)d_in[22];
    const int* nids = (const int*)d_in[23];

    const int N = in_sizes[2] / HD;
    const int E = in_sizes[1];
    const int U = in_sizes[23];
    const int C = in_sizes[20];
    const int NP = (N + 127) & ~127;   // row-padded for 128-row GEMM tiles
    const int NB1K = (N + 1023) / 1024; // scan blocks

    float* out  = (float*)d_out;
    float* pred = out;          // [C]
    float* hout = out + C;      // [N,H]

    // workspace layout (16B-aligned chunks); zsb aliases nfb (dead after agg_feat)
    char* p = (char*)d_ws;
    auto alloc = [&](size_t bytes) { char* r = p; p += (bytes + 15) & ~(size_t)15; return r; };
    float* deg    = (float*)alloc((size_t)N * 4);
    float* dinv   = (float*)alloc((size_t)N * 4);
    float* norm_s = (float*)alloc((size_t)E * 4);
    float* pooled = (float*)alloc(HD * 4);
    int*   counts = (int*)alloc((size_t)N * 4);
    int*   row_ptr= (int*)alloc((size_t)(N + 1) * 4);
    int*   cursor = (int*)alloc((size_t)N * 4);
    int*   src_s  = (int*)alloc((size_t)E * 4);
    int*   bsums  = (int*)alloc((size_t)1024 * 4);
    ushort* nfb   = (ushort*)alloc((size_t)NP * HD * 2);  // -> zsb after agg
    ushort* aggb  = (ushort*)alloc((size_t)NP * HD * 2);
    ushort* h0b   = (ushort*)alloc((size_t)NP * HD * 2);
    ushort* hqb   = (ushort*)alloc((size_t)NP * HD * 2);
    ushort* BT    = (ushort*)alloc((size_t)3 * 128 * 256 * 2);
    float* lb2    = (float*)alloc(384 * 4);
    ushort* zsb   = nfb;  // alias

    hipMemsetAsync(counts, 0, (size_t)N * sizeof(int), stream);
    hipMemsetAsync(pooled, 0, HD * sizeof(float), stream);

    int prep_items = N * (HD / 8);
    prep_kernel<<<(prep_items + 255) / 256, 256, 0, stream>>>(node_feat, h0, nfb, h0b, deg, N);
    edge_accum_kernel<<<(E + 255) / 256, 256, 0, stream>>>(dst, edge_w, deg, counts, E);
    dinv_kernel<<<(N + 255) / 256, 256, 0, stream>>>(deg, dinv, N);
    scan_partial_kernel<<<NB1K, 256, 0, stream>>>(counts, bsums, N);
    scan_bsums_kernel<<<1, 1024, 0, stream>>>(bsums, row_ptr + N, NB1K);
    scan_final_kernel<<<NB1K, 256, 0, stream>>>(counts, bsums, row_ptr, cursor, N);
    fill_kernel<<<(E + 255) / 256, 256, 0, stream>>>(src, dst, edge_w, dinv, cursor,
                                                     src_s, norm_s, E);
    dim3 fg(3, 16);
    fuse_weights_kernel<<<fg, 256, 0, stream>>>(Wz, Wr, Wh, lzW, lrW, lhW, BT);
    lb2_kernel<<<3, 128, 0, stream>>>(lzW, lrW, lhW, bz, br, bh, lzb, lrb, lhb, lb2);
    agg_feat_kernel<<<(N + 3) / 4, 256, 0, stream>>>(
        (const unsigned*)nfb, dinv, row_ptr, src_s, norm_s, (unsigned*)aggb, N);
    dim3 zg(NP / 128, 2);
    gemm_zr_kernel<<<zg, 256, 0, stream>>>(aggb, h0b, BT, lb2, zsb, hqb, NP);
    gemm_ht_kernel<<<NP / 128, 256, 0, stream>>>(aggb, hqb, h0b, zsb, BT, lb2, hout, N);
    pool_kernel<<<512, 128, 0, stream>>>(hout, nids, pooled, U);
    decoder_kernel<<<1, 128, 0, stream>>>(pooled, 1.0f / (float)U,
                                          linW, linb, dnW, dnb, outW, outb, pred, C);
}

// Round 7
// 386.206 us; speedup vs baseline: 1.3242x; 1.0342x over previous
//
#include <hip/hip_runtime.h>
#include <math.h>

// TGCN: bf16 feature-space GCN aggregation (fp32 accum) -> single fused GRU
// kernel (z,r,hq,ht in one pass, LDS-staged A, pre-fused weights):
//   z/r: [agg|h0] @ [Wg@lgW_top ; lgW_bot],  ht: [agg|h0*r] @ [Wh@lhW_top ; lhW_bot]
// CSR-by-dst via hierarchical 3-kernel scan. No float atomic scatter.

#define HD 128

typedef __attribute__((ext_vector_type(8))) short short8;
typedef __attribute__((ext_vector_type(4))) float f32x4;

__device__ __forceinline__ ushort f2bf(float f) {
    union { float f; unsigned u; } v; v.f = f;
    unsigned r = (v.u + 0x7FFFu + ((v.u >> 16) & 1u)) >> 16;
    return (ushort)r;
}
__device__ __forceinline__ float bf2f(ushort h) {
    union { unsigned u; float f; } v; v.u = ((unsigned)h) << 16;
    return v.f;
}
__device__ __forceinline__ float bflo(unsigned u) {
    union { unsigned u; float f; } v; v.u = u << 16; return v.f;
}
__device__ __forceinline__ float bfhi(unsigned u) {
    union { unsigned u; float f; } v; v.u = u & 0xFFFF0000u; return v.f;
}

// nf -> bf16, h0 -> bf16 (vectorized), plus deg := 1.0 init
__global__ void prep_kernel(const float* __restrict__ nf, const float* __restrict__ h0,
                            ushort* __restrict__ nfb, ushort* __restrict__ h0b,
                            float* deg, int n) {
    int idx = blockIdx.x * 256 + threadIdx.x;
    int total8 = n * (HD / 8);
    if (idx < total8) {
        const float4* p = (const float4*)(nf + (size_t)idx * 8);
        float4 x = p[0], y = p[1];
        short8 o;
        o[0] = (short)f2bf(x.x); o[1] = (short)f2bf(x.y);
        o[2] = (short)f2bf(x.z); o[3] = (short)f2bf(x.w);
        o[4] = (short)f2bf(y.x); o[5] = (short)f2bf(y.y);
        o[6] = (short)f2bf(y.z); o[7] = (short)f2bf(y.w);
        *(short8*)(nfb + (size_t)idx * 8) = o;
        const float4* q = (const float4*)(h0 + (size_t)idx * 8);
        float4 a = q[0], b = q[1];
        short8 o2;
        o2[0] = (short)f2bf(a.x); o2[1] = (short)f2bf(a.y);
        o2[2] = (short)f2bf(a.z); o2[3] = (short)f2bf(a.w);
        o2[4] = (short)f2bf(b.x); o2[5] = (short)f2bf(b.y);
        o2[6] = (short)f2bf(b.z); o2[7] = (short)f2bf(b.w);
        *(short8*)(h0b + (size_t)idx * 8) = o2;
    }
    if (idx < n) deg[idx] = 1.0f;
}

__global__ void edge_accum_kernel(const int* __restrict__ dst,
                                  const float* __restrict__ w,
                                  float* deg, int* counts, int E) {
    int e = blockIdx.x * blockDim.x + threadIdx.x;
    if (e < E) {
        int d = dst[e];
        atomicAdd(&deg[d], w[e]);
        atomicAdd(&counts[d], 1);
    }
}

__global__ void dinv_kernel(const float* __restrict__ deg, float* dinv, int n) {
    int i = blockIdx.x * blockDim.x + threadIdx.x;
    if (i < n) {
        float d = deg[i];
        dinv[i] = (d > 0.0f) ? rsqrtf(d) : 0.0f;
    }
}

// ---- hierarchical scan: partial sums (1024 elems / 256-thr block) ----
__global__ __launch_bounds__(256) void scan_partial_kernel(
        const int* __restrict__ counts, int* __restrict__ bsums, int n) {
    __shared__ int ws[4];
    int b = blockIdx.x, t = threadIdx.x;
    int idx = b * 1024 + t * 4;
    int4 v = {0, 0, 0, 0};
    if (idx + 3 < n) v = *(const int4*)(counts + idx);
    else {
        if (idx < n) v.x = counts[idx];
        if (idx + 1 < n) v.y = counts[idx + 1];
        if (idx + 2 < n) v.z = counts[idx + 2];
        if (idx + 3 < n) v.w = counts[idx + 3];
    }
    int s = v.x + v.y + v.z + v.w;
    for (int off = 1; off < 64; off <<= 1) s += __shfl_xor(s, off, 64);
    if ((t & 63) == 0) ws[t >> 6] = s;
    __syncthreads();
    if (t == 0) bsums[b] = ws[0] + ws[1] + ws[2] + ws[3];
}

// scan of nb (<=1024) block sums -> exclusive; writes row_ptr[n]
__global__ __launch_bounds__(1024) void scan_bsums_kernel(
        int* __restrict__ bsums, int* __restrict__ rp_total, int nb) {
    __shared__ int ws[16];
    int t = threadIdx.x;
    int v = (t < nb) ? bsums[t] : 0;
    int lane = t & 63, wid = t >> 6;
    int x = v;
    for (int off = 1; off < 64; off <<= 1) {
        int y = __shfl_up(x, off, 64);
        if (lane >= off) x += y;
    }
    if (lane == 63) ws[wid] = x;
    __syncthreads();
    if (wid == 0) {
        int s = (lane < 16) ? ws[lane] : 0;
        for (int off = 1; off < 16; off <<= 1) {
            int y = __shfl_up(s, off, 64);
            if (lane >= off) s += y;
        }
        if (lane < 16) ws[lane] = s;
    }
    __syncthreads();
    int excl = x - v + ((wid == 0) ? 0 : ws[wid - 1]);
    if (t < nb) bsums[t] = excl;
    if (t == nb - 1) *rp_total = excl + v;
}

// final: per-block local scan + block offset -> row_ptr, cursor
__global__ __launch_bounds__(256) void scan_final_kernel(
        const int* __restrict__ counts, const int* __restrict__ bsums,
        int* __restrict__ row_ptr, int* __restrict__ cursor, int n) {
    __shared__ int ws[4];
    int b = blockIdx.x, t = threadIdx.x;
    int idx = b * 1024 + t * 4;
    int4 v = {0, 0, 0, 0};
    if (idx + 3 < n) v = *(const int4*)(counts + idx);
    else {
        if (idx < n) v.x = counts[idx];
        if (idx + 1 < n) v.y = counts[idx + 1];
        if (idx + 2 < n) v.z = counts[idx + 2];
        if (idx + 3 < n) v.w = counts[idx + 3];
    }
    int s = v.x + v.y + v.z + v.w;
    int lane = t & 63, wid = t >> 6;
    int x = s;
    for (int off = 1; off < 64; off <<= 1) {
        int y = __shfl_up(x, off, 64);
        if (lane >= off) x += y;
    }
    if (lane == 63) ws[wid] = x;
    __syncthreads();
    int woff = 0;
    for (int wv = 0; wv < wid; ++wv) woff += ws[wv];
    int run = bsums[b] + woff + x - s;
    int4 rp;
    rp.x = run; rp.y = run + v.x; rp.z = rp.y + v.y; rp.w = rp.z + v.z;
    if (idx + 3 < n) {
        *(int4*)(row_ptr + idx) = rp;
        *(int4*)(cursor + idx) = rp;
    } else {
        if (idx < n) { row_ptr[idx] = rp.x; cursor[idx] = rp.x; }
        if (idx + 1 < n) { row_ptr[idx + 1] = rp.y; cursor[idx + 1] = rp.y; }
        if (idx + 2 < n) { row_ptr[idx + 2] = rp.z; cursor[idx + 2] = rp.z; }
        if (idx + 3 < n) { row_ptr[idx + 3] = rp.w; cursor[idx + 3] = rp.w; }
    }
}

__global__ void fill_kernel(const int* __restrict__ src, const int* __restrict__ dst,
                            const float* __restrict__ w, const float* __restrict__ dinv,
                            int* cursor, int* src_s, float* norm_s, int E) {
    int e = blockIdx.x * blockDim.x + threadIdx.x;
    if (e < E) {
        int s = src[e], d = dst[e];
        int p = atomicAdd(&cursor[d], 1);
        src_s[p] = s;
        norm_s[p] = dinv[s] * w[e] * dinv[d];
    }
}

// Fused-weight build, parallel+coalesced. grid (3,16), 256 thr.
__global__ __launch_bounds__(256) void fuse_weights_kernel(
        const float* __restrict__ Wz, const float* __restrict__ Wr,
        const float* __restrict__ Wh,
        const float* __restrict__ lzW, const float* __restrict__ lrW,
        const float* __restrict__ lhW,
        ushort* __restrict__ BT) {
    int g = blockIdx.x, kt = blockIdx.y;
    const float* W  = (g == 0) ? Wz  : (g == 1) ? Wr  : Wh;
    const float* lW = (g == 0) ? lzW : (g == 1) ? lrW : lhW;
    int t = threadIdx.x;
    int j = t & 127, kh = t >> 7;          // kh in {0,1}
    int k0 = kt * 8 + kh * 4;
    float m0 = 0.f, m1 = 0.f, m2 = 0.f, m3 = 0.f;
    for (int mm = 0; mm < 128; ++mm) {
        float lv = lW[mm * 128 + j];       // coalesced across j
        m0 += W[(k0 + 0) * 128 + mm] * lv; // wave-uniform -> broadcast
        m1 += W[(k0 + 1) * 128 + mm] * lv;
        m2 += W[(k0 + 2) * 128 + mm] * lv;
        m3 += W[(k0 + 3) * 128 + mm] * lv;
    }
    ushort* dstc = BT + ((size_t)g * 128 + j) * 256;
    dstc[k0 + 0] = f2bf(m0); dstc[k0 + 1] = f2bf(m1);
    dstc[k0 + 2] = f2bf(m2); dstc[k0 + 3] = f2bf(m3);
#pragma unroll
    for (int u = 0; u < 4; ++u) {
        int mm = k0 + u;
        dstc[128 + mm] = f2bf(lW[(128 + mm) * 128 + j]);
    }
}

// lb2[g][j] = lgb[j] + sum_m bg[m]*lgW_top[m][j]
__global__ __launch_bounds__(128) void lb2_kernel(
        const float* __restrict__ lzW, const float* __restrict__ lrW,
        const float* __restrict__ lhW,
        const float* __restrict__ bz, const float* __restrict__ br,
        const float* __restrict__ bh,
        const float* __restrict__ lzb, const float* __restrict__ lrb,
        const float* __restrict__ lhb,
        float* __restrict__ lb2) {
    int g = blockIdx.x, j = threadIdx.x;
    const float* lW = (g == 0) ? lzW : (g == 1) ? lrW : lhW;
    const float* bg = (g == 0) ? bz  : (g == 1) ? br  : bh;
    const float* lb = (g == 0) ? lzb : (g == 1) ? lrb : lhb;
    float s = lb[j];
    for (int mm = 0; mm < 128; ++mm) s += bg[mm] * lW[mm * 128 + j];
    lb2[g * 128 + j] = s;
}

// aggb[i,:] = bf16( dinv[i]^2 * nfb[i,:] + sum_e norm[e] * nfb[src[e],:] )
__global__ __launch_bounds__(256) void agg_feat_kernel(
        const unsigned* __restrict__ nfb32, const float* __restrict__ dinv,
        const int* __restrict__ row_ptr, const int* __restrict__ src_s,
        const float* __restrict__ norm_s, unsigned* __restrict__ aggb32, int n) {
    int t = threadIdx.x & 63;            // column pair
    int grp = threadIdx.x >> 6;
    int i = blockIdx.x * 4 + grp;
    if (i >= n) return;
    float di = dinv[i];
    unsigned uself = nfb32[(size_t)i * 64 + t];
    float a0 = di * di * bflo(uself);
    float a1 = di * di * bfhi(uself);
    int e0 = row_ptr[i], e1 = row_ptr[i + 1];
    for (int e = e0; e < e1; e += 8) {
        unsigned v[8]; float w[8];
#pragma unroll
        for (int u = 0; u < 8; ++u) {
            int ee = e + u;
            bool ok = ee < e1;
            int s = ok ? src_s[ee] : src_s[e0];
            w[u] = ok ? norm_s[ee] : 0.0f;
            v[u] = nfb32[(size_t)s * 64 + t];
        }
#pragma unroll
        for (int u = 0; u < 8; ++u) {
            a0 += w[u] * bflo(v[u]);
            a1 += w[u] * bfhi(v[u]);
        }
    }
    aggb32[(size_t)i * 64 + t] = (unsigned)f2bf(a0) | ((unsigned)f2bf(a1) << 16);
}

// Fused GRU: one 64-row tile per block, 4 waves x 16 rows.
// Phases (all K=256 MFMA GEMMs, B broadcast from L2):
//   z = sigmoid([agg|h0]@BTz + lb2z)        (kept in regs)
//   r = sigmoid([agg|h0]@BTr + lb2r); hq = r*h0 -> LDS (over h0)
//   ht = tanh([agg|hq]@BTh + lb2h); h_new = z*h0 + (1-z)*ht -> coalesced fp32
__global__ __launch_bounds__(256) void gru_fused_kernel(
        const ushort* __restrict__ aggb, const ushort* __restrict__ h0b,
        const ushort* __restrict__ BT, const float* __restrict__ lb2,
        float* __restrict__ hout, int n) {
    __shared__ ushort Aag[64][136];   // agg tile (pad 8 -> 2-way bank alias, free)
    __shared__ ushort Ah0[64][136];   // h0 tile; overwritten with hq after r-phase
    int t = threadIdx.x;
    int i0 = blockIdx.x * 64;

    // stage 64 rows x 128 cols of agg + h0 (coalesced short8)
    for (int c = t; c < 1024; c += 256) {
        int row = c >> 4, c8 = c & 15;
        size_t gp = (size_t)(i0 + row) * HD + c8 * 8;
        *(short8*)&Aag[row][c8 * 8] = *(const short8*)(aggb + gp);
        *(short8*)&Ah0[row][c8 * 8] = *(const short8*)(h0b + gp);
    }
    __syncthreads();

    int w = t >> 6, lane = t & 63;
    int rlo = lane & 15, koff = (lane >> 4) * 8, rbase = (lane >> 4) * 4;
    int rw = w * 16;                   // wave's row base within tile

    f32x4 acc[8];
    const f32x4 zero4 = {0.f, 0.f, 0.f, 0.f};
    float zv[32], hv[32];

    // ---- phase Z (gate 0) ----
#pragma unroll
    for (int cf = 0; cf < 8; ++cf) acc[cf] = zero4;
#pragma unroll
    for (int ks = 0; ks < 8; ++ks) {
        short8 af = (ks < 4)
            ? *(const short8*)&Aag[rw + rlo][ks * 32 + koff]
            : *(const short8*)&Ah0[rw + rlo][(ks - 4) * 32 + koff];
#pragma unroll
        for (int cf = 0; cf < 8; ++cf) {
            short8 bf = *(const short8*)(BT + (size_t)(cf * 16 + rlo) * 256 + ks * 32 + koff);
            acc[cf] = __builtin_amdgcn_mfma_f32_16x16x32_bf16(af, bf, acc[cf], 0, 0, 0);
        }
    }
#pragma unroll
    for (int cf = 0; cf < 8; ++cf) {
        int lc = cf * 16 + rlo;
        float bv = lb2[lc];
#pragma unroll
        for (int i = 0; i < 4; ++i) {
            zv[cf * 4 + i] = 1.0f / (1.0f + expf(-(acc[cf][i] + bv)));
            hv[cf * 4 + i] = bf2f(Ah0[rw + rbase + i][lc]);
        }
    }

    // ---- phase R (gate 1) ----
#pragma unroll
    for (int cf = 0; cf < 8; ++cf) acc[cf] = zero4;
#pragma unroll
    for (int ks = 0; ks < 8; ++ks) {
        short8 af = (ks < 4)
            ? *(const short8*)&Aag[rw + rlo][ks * 32 + koff]
            : *(const short8*)&Ah0[rw + rlo][(ks - 4) * 32 + koff];
#pragma unroll
        for (int cf = 0; cf < 8; ++cf) {
            short8 bf = *(const short8*)(BT + (size_t)(128 + cf * 16 + rlo) * 256 + ks * 32 + koff);
            acc[cf] = __builtin_amdgcn_mfma_f32_16x16x32_bf16(af, bf, acc[cf], 0, 0, 0);
        }
    }
    __syncthreads();   // everyone done reading Ah0 as h0
#pragma unroll
    for (int cf = 0; cf < 8; ++cf) {
        int lc = cf * 16 + rlo;
        float bv = lb2[128 + lc];
#pragma unroll
        for (int i = 0; i < 4; ++i) {
            float r = 1.0f / (1.0f + expf(-(acc[cf][i] + bv)));
            Ah0[rw + rbase + i][lc] = f2bf(r * hv[cf * 4 + i]);  // hq
        }
    }
    __syncthreads();

    // ---- phase HT (gate 2): A = [agg | hq] ----
#pragma unroll
    for (int cf = 0; cf < 8; ++cf) acc[cf] = zero4;
#pragma unroll
    for (int ks = 0; ks < 8; ++ks) {
        short8 af = (ks < 4)
            ? *(const short8*)&Aag[rw + rlo][ks * 32 + koff]
            : *(const short8*)&Ah0[rw + rlo][(ks - 4) * 32 + koff];
#pragma unroll
        for (int cf = 0; cf < 8; ++cf) {
            short8 bf = *(const short8*)(BT + (size_t)(256 + cf * 16 + rlo) * 256 + ks * 32 + koff);
            acc[cf] = __builtin_amdgcn_mfma_f32_16x16x32_bf16(af, bf, acc[cf], 0, 0, 0);
        }
    }
#pragma unroll
    for (int cf = 0; cf < 8; ++cf) {
        int lc = cf * 16 + rlo;
        float bv = lb2[256 + lc];
#pragma unroll
        for (int i = 0; i < 4; ++i) {
            int row = i0 + rw + rbase + i;
            if (row < n) {
                float ht = tanhf(acc[cf][i] + bv);
                float z = zv[cf * 4 + i];
                hout[(size_t)row * HD + lc] = z * hv[cf * 4 + i] + (1.0f - z) * ht;
            }
        }
    }
}

__global__ __launch_bounds__(128) void pool_kernel(
        const float* __restrict__ hout, const int* __restrict__ nids,
        float* pooled, int U) {
    int t = threadIdx.x;
    float pa = 0.0f;
    for (int u = blockIdx.x; u < U; u += gridDim.x) {
        int nid = nids[u];
        pa += fmaxf(hout[(size_t)nid * HD + t], 0.0f);
    }
    atomicAdd(&pooled[t], pa);
}

__global__ __launch_bounds__(128) void decoder_kernel(
        const float* __restrict__ pooled, float invU,
        const float* __restrict__ linW, const float* __restrict__ linb,
        const float* __restrict__ dnW, const float* __restrict__ dnb,
        const float* __restrict__ outW, const float* __restrict__ outb,
        float* pred, int C) {
    __shared__ float sh[HD];
    int t = threadIdx.x;
    sh[t] = pooled[t] * invU;
    __syncthreads();
    float v = linb[t];
    for (int k = 0; k < HD; ++k) v += sh[k] * linW[k * HD + t];
    __syncthreads();
    sh[t] = v;
    __syncthreads();
    float d = dnb[t];
    for (int k = 0; k < HD; ++k) d += sh[k] * dnW[k * HD + t];
    d = fmaxf(d, 0.0f);
    __syncthreads();
    sh[t] = d;
    __syncthreads();
    if (t < C) {
        float p = outb[t];
        for (int k = 0; k < HD; ++k) p += sh[k] * outW[k * C + t];
        pred[t] = 1.0f / (1.0f + expf(-p));
    }
}

extern "C" void kernel_launch(void* const* d_in, const int* in_sizes, int n_in,
                              void* d_out, int out_size, void* d_ws, size_t ws_size,
                              hipStream_t stream) {
    const float* node_feat = (const float*)d_in[0];
    const float* edge_w    = (const float*)d_in[1];
    const float* h0        = (const float*)d_in[2];
    const float* Wz  = (const float*)d_in[3];  const float* bz  = (const float*)d_in[4];
    const float* Wr  = (const float*)d_in[5];  const float* br  = (const float*)d_in[6];
    const float* Wh  = (const float*)d_in[7];  const float* bh  = (const float*)d_in[8];
    const float* lzW = (const float*)d_in[9];  const float* lzb = (const float*)d_in[10];
    const float* lrW = (const float*)d_in[11]; const float* lrb = (const float*)d_in[12];
    const float* lhW = (const float*)d_in[13]; const float* lhb = (const float*)d_in[14];
    const float* linW= (const float*)d_in[15]; const float* linb= (const float*)d_in[16];
    const float* dnW = (const float*)d_in[17]; const float* dnb = (const float*)d_in[18];
    const float* outW= (const float*)d_in[19]; const float* outb= (const float*)d_in[20];
    const int* src  = (const int*)d_in[21];
    const int* dst  = (const int*)d_in[22];
    const int* nids = (const int*)d_in[23];

    const int N = in_sizes[2] / HD;
    const int E = in_sizes[1];
    const int U = in_sizes[23];
    const int C = in_sizes[20];
    const int NP = (N + 127) & ~127;    // row-padded
    const int NB1K = (N + 1023) / 1024; // scan blocks

    float* out  = (float*)d_out;
    float* pred = out;          // [C]
    float* hout = out + C;      // [N,H]

    // workspace layout (16B-aligned chunks)
    char* p = (char*)d_ws;
    auto alloc = [&](size_t bytes) { char* r = p; p += (bytes + 15) & ~(size_t)15; return r; };
    float* deg    = (float*)alloc((size_t)N * 4);
    float* dinv   = (float*)alloc((size_t)N * 4);
    float* norm_s = (float*)alloc((size_t)E * 4);
    float* pooled = (float*)alloc(HD * 4);
    int*   counts = (int*)alloc((size_t)N * 4);
    int*   row_ptr= (int*)alloc((size_t)(N + 1) * 4);
    int*   cursor = (int*)alloc((size_t)N * 4);
    int*   src_s  = (int*)alloc((size_t)E * 4);
    int*   bsums  = (int*)alloc((size_t)1024 * 4);
    ushort* nfb   = (ushort*)alloc((size_t)NP * HD * 2);
    ushort* aggb  = (ushort*)alloc((size_t)NP * HD * 2);
    ushort* h0b   = (ushort*)alloc((size_t)NP * HD * 2);
    ushort* BT    = (ushort*)alloc((size_t)3 * 128 * 256 * 2);
    float* lb2    = (float*)alloc(384 * 4);

    hipMemsetAsync(counts, 0, (size_t)N * sizeof(int), stream);
    hipMemsetAsync(pooled, 0, HD * sizeof(float), stream);

    int prep_items = N * (HD / 8);
    prep_kernel<<<(prep_items + 255) / 256, 256, 0, stream>>>(node_feat, h0, nfb, h0b, deg, N);
    edge_accum_kernel<<<(E + 255) / 256, 256, 0, stream>>>(dst, edge_w, deg, counts, E);
    dinv_kernel<<<(N + 255) / 256, 256, 0, stream>>>(deg, dinv, N);
    scan_partial_kernel<<<NB1K, 256, 0, stream>>>(counts, bsums, N);
    scan_bsums_kernel<<<1, 1024, 0, stream>>>(bsums, row_ptr + N, NB1K);
    scan_final_kernel<<<NB1K, 256, 0, stream>>>(counts, bsums, row_ptr, cursor, N);
    fill_kernel<<<(E + 255) / 256, 256, 0, stream>>>(src, dst, edge_w, dinv, cursor,
                                                     src_s, norm_s, E);
    dim3 fg(3, 16);
    fuse_weights_kernel<<<fg, 256, 0, stream>>>(Wz, Wr, Wh, lzW, lrW, lhW, BT);
    lb2_kernel<<<3, 128, 0, stream>>>(lzW, lrW, lhW, bz, br, bh, lzb, lrb, lhb, lb2);
    agg_feat_kernel<<<(N + 3) / 4, 256, 0, stream>>>(
        (const unsigned*)nfb, dinv, row_ptr, src_s, norm_s, (unsigned*)aggb, N);
    gru_fused_kernel<<<NP / 64, 256, 0, stream>>>(aggb, h0b, BT, lb2, hout, N);
    pool_kernel<<<512, 128, 0, stream>>>(hout, nids, pooled, U);
    decoder_kernel<<<1, 128, 0, stream>>>(pooled, 1.0f / (float)U,
                                          linW, linb, dnW, dnb, outW, outb, pred, C);
}

// Round 8
// 325.490 us; speedup vs baseline: 1.5712x; 1.1865x over previous
//
#include <hip/hip_runtime.h>
#include <math.h>

// TGCN: bf16 feature-space GCN aggregation (fp32 accum) -> single fused GRU
// kernel (z,r,hq,ht in one pass; B-slice in REGISTERS per wave, A in LDS):
//   z/r: [agg|h0] @ [Wg@lgW_top ; lgW_bot],  ht: [agg|h0*r] @ [Wh@lhW_top ; lhW_bot]
// CSR-by-dst via hierarchical 3-kernel scan. No float atomic scatter.

#define HD 128

typedef __attribute__((ext_vector_type(8))) short short8;
typedef __attribute__((ext_vector_type(4))) float f32x4;

__device__ __forceinline__ ushort f2bf(float f) {
    union { float f; unsigned u; } v; v.f = f;
    unsigned r = (v.u + 0x7FFFu + ((v.u >> 16) & 1u)) >> 16;
    return (ushort)r;
}
__device__ __forceinline__ float bf2f(ushort h) {
    union { unsigned u; float f; } v; v.u = ((unsigned)h) << 16;
    return v.f;
}
__device__ __forceinline__ float bflo(unsigned u) {
    union { unsigned u; float f; } v; v.u = u << 16; return v.f;
}
__device__ __forceinline__ float bfhi(unsigned u) {
    union { unsigned u; float f; } v; v.u = u & 0xFFFF0000u; return v.f;
}
__device__ __forceinline__ float fast_sigmoid(float x) {
    return 1.0f / (1.0f + __expf(-x));
}
__device__ __forceinline__ float fast_tanh(float x) {
    float e = __expf(-2.0f * fabsf(x));
    float m = (1.0f - e) / (1.0f + e);
    return copysignf(m, x);
}

// nf -> bf16, h0 -> bf16 (vectorized), plus deg := 1.0 init
__global__ void prep_kernel(const float* __restrict__ nf, const float* __restrict__ h0,
                            ushort* __restrict__ nfb, ushort* __restrict__ h0b,
                            float* deg, int n) {
    int idx = blockIdx.x * 256 + threadIdx.x;
    int total8 = n * (HD / 8);
    if (idx < total8) {
        const float4* p = (const float4*)(nf + (size_t)idx * 8);
        float4 x = p[0], y = p[1];
        short8 o;
        o[0] = (short)f2bf(x.x); o[1] = (short)f2bf(x.y);
        o[2] = (short)f2bf(x.z); o[3] = (short)f2bf(x.w);
        o[4] = (short)f2bf(y.x); o[5] = (short)f2bf(y.y);
        o[6] = (short)f2bf(y.z); o[7] = (short)f2bf(y.w);
        *(short8*)(nfb + (size_t)idx * 8) = o;
        const float4* q = (const float4*)(h0 + (size_t)idx * 8);
        float4 a = q[0], b = q[1];
        short8 o2;
        o2[0] = (short)f2bf(a.x); o2[1] = (short)f2bf(a.y);
        o2[2] = (short)f2bf(a.z); o2[3] = (short)f2bf(a.w);
        o2[4] = (short)f2bf(b.x); o2[5] = (short)f2bf(b.y);
        o2[6] = (short)f2bf(b.z); o2[7] = (short)f2bf(b.w);
        *(short8*)(h0b + (size_t)idx * 8) = o2;
    }
    if (idx < n) deg[idx] = 1.0f;
}

__global__ void edge_accum_kernel(const int* __restrict__ dst,
                                  const float* __restrict__ w,
                                  float* deg, int* counts, int E) {
    int e = blockIdx.x * blockDim.x + threadIdx.x;
    if (e < E) {
        int d = dst[e];
        atomicAdd(&deg[d], w[e]);
        atomicAdd(&counts[d], 1);
    }
}

__global__ void dinv_kernel(const float* __restrict__ deg, float* dinv, int n) {
    int i = blockIdx.x * blockDim.x + threadIdx.x;
    if (i < n) {
        float d = deg[i];
        dinv[i] = (d > 0.0f) ? rsqrtf(d) : 0.0f;
    }
}

// ---- hierarchical scan: partial sums (1024 elems / 256-thr block) ----
__global__ __launch_bounds__(256) void scan_partial_kernel(
        const int* __restrict__ counts, int* __restrict__ bsums, int n) {
    __shared__ int ws[4];
    int b = blockIdx.x, t = threadIdx.x;
    int idx = b * 1024 + t * 4;
    int4 v = {0, 0, 0, 0};
    if (idx + 3 < n) v = *(const int4*)(counts + idx);
    else {
        if (idx < n) v.x = counts[idx];
        if (idx + 1 < n) v.y = counts[idx + 1];
        if (idx + 2 < n) v.z = counts[idx + 2];
        if (idx + 3 < n) v.w = counts[idx + 3];
    }
    int s = v.x + v.y + v.z + v.w;
    for (int off = 1; off < 64; off <<= 1) s += __shfl_xor(s, off, 64);
    if ((t & 63) == 0) ws[t >> 6] = s;
    __syncthreads();
    if (t == 0) bsums[b] = ws[0] + ws[1] + ws[2] + ws[3];
}

// scan of nb (<=1024) block sums -> exclusive; writes row_ptr[n]
__global__ __launch_bounds__(1024) void scan_bsums_kernel(
        int* __restrict__ bsums, int* __restrict__ rp_total, int nb) {
    __shared__ int ws[16];
    int t = threadIdx.x;
    int v = (t < nb) ? bsums[t] : 0;
    int lane = t & 63, wid = t >> 6;
    int x = v;
    for (int off = 1; off < 64; off <<= 1) {
        int y = __shfl_up(x, off, 64);
        if (lane >= off) x += y;
    }
    if (lane == 63) ws[wid] = x;
    __syncthreads();
    if (wid == 0) {
        int s = (lane < 16) ? ws[lane] : 0;
        for (int off = 1; off < 16; off <<= 1) {
            int y = __shfl_up(s, off, 64);
            if (lane >= off) s += y;
        }
        if (lane < 16) ws[lane] = s;
    }
    __syncthreads();
    int excl = x - v + ((wid == 0) ? 0 : ws[wid - 1]);
    if (t < nb) bsums[t] = excl;
    if (t == nb - 1) *rp_total = excl + v;
}

// final: per-block local scan + block offset -> row_ptr, cursor
__global__ __launch_bounds__(256) void scan_final_kernel(
        const int* __restrict__ counts, const int* __restrict__ bsums,
        int* __restrict__ row_ptr, int* __restrict__ cursor, int n) {
    __shared__ int ws[4];
    int b = blockIdx.x, t = threadIdx.x;
    int idx = b * 1024 + t * 4;
    int4 v = {0, 0, 0, 0};
    if (idx + 3 < n) v = *(const int4*)(counts + idx);
    else {
        if (idx < n) v.x = counts[idx];
        if (idx + 1 < n) v.y = counts[idx + 1];
        if (idx + 2 < n) v.z = counts[idx + 2];
        if (idx + 3 < n) v.w = counts[idx + 3];
    }
    int s = v.x + v.y + v.z + v.w;
    int lane = t & 63, wid = t >> 6;
    int x = s;
    for (int off = 1; off < 64; off <<= 1) {
        int y = __shfl_up(x, off, 64);
        if (lane >= off) x += y;
    }
    if (lane == 63) ws[wid] = x;
    __syncthreads();
    int woff = 0;
    for (int wv = 0; wv < wid; ++wv) woff += ws[wv];
    int run = bsums[b] + woff + x - s;
    int4 rp;
    rp.x = run; rp.y = run + v.x; rp.z = rp.y + v.y; rp.w = rp.z + v.z;
    if (idx + 3 < n) {
        *(int4*)(row_ptr + idx) = rp;
        *(int4*)(cursor + idx) = rp;
    } else {
        if (idx < n) { row_ptr[idx] = rp.x; cursor[idx] = rp.x; }
        if (idx + 1 < n) { row_ptr[idx + 1] = rp.y; cursor[idx + 1] = rp.y; }
        if (idx + 2 < n) { row_ptr[idx + 2] = rp.z; cursor[idx + 2] = rp.z; }
        if (idx + 3 < n) { row_ptr[idx + 3] = rp.w; cursor[idx + 3] = rp.w; }
    }
}

__global__ void fill_kernel(const int* __restrict__ src, const int* __restrict__ dst,
                            const float* __restrict__ w, const float* __restrict__ dinv,
                            int* cursor, int* src_s, float* norm_s, int E) {
    int e = blockIdx.x * blockDim.x + threadIdx.x;
    if (e < E) {
        int s = src[e], d = dst[e];
        int p = atomicAdd(&cursor[d], 1);
        src_s[p] = s;
        norm_s[p] = dinv[s] * w[e] * dinv[d];
    }
}

// Fused-weight build, parallel+coalesced. grid (3,16), 256 thr.
__global__ __launch_bounds__(256) void fuse_weights_kernel(
        const float* __restrict__ Wz, const float* __restrict__ Wr,
        const float* __restrict__ Wh,
        const float* __restrict__ lzW, const float* __restrict__ lrW,
        const float* __restrict__ lhW,
        ushort* __restrict__ BT) {
    int g = blockIdx.x, kt = blockIdx.y;
    const float* W  = (g == 0) ? Wz  : (g == 1) ? Wr  : Wh;
    const float* lW = (g == 0) ? lzW : (g == 1) ? lrW : lhW;
    int t = threadIdx.x;
    int j = t & 127, kh = t >> 7;          // kh in {0,1}
    int k0 = kt * 8 + kh * 4;
    float m0 = 0.f, m1 = 0.f, m2 = 0.f, m3 = 0.f;
    for (int mm = 0; mm < 128; ++mm) {
        float lv = lW[mm * 128 + j];       // coalesced across j
        m0 += W[(k0 + 0) * 128 + mm] * lv; // wave-uniform -> broadcast
        m1 += W[(k0 + 1) * 128 + mm] * lv;
        m2 += W[(k0 + 2) * 128 + mm] * lv;
        m3 += W[(k0 + 3) * 128 + mm] * lv;
    }
    ushort* dstc = BT + ((size_t)g * 128 + j) * 256;
    dstc[k0 + 0] = f2bf(m0); dstc[k0 + 1] = f2bf(m1);
    dstc[k0 + 2] = f2bf(m2); dstc[k0 + 3] = f2bf(m3);
#pragma unroll
    for (int u = 0; u < 4; ++u) {
        int mm = k0 + u;
        dstc[128 + mm] = f2bf(lW[(128 + mm) * 128 + j]);
    }
}

// lb2[g][j] = lgb[j] + sum_m bg[m]*lgW_top[m][j]
__global__ __launch_bounds__(128) void lb2_kernel(
        const float* __restrict__ lzW, const float* __restrict__ lrW,
        const float* __restrict__ lhW,
        const float* __restrict__ bz, const float* __restrict__ br,
        const float* __restrict__ bh,
        const float* __restrict__ lzb, const float* __restrict__ lrb,
        const float* __restrict__ lhb,
        float* __restrict__ lb2) {
    int g = blockIdx.x, j = threadIdx.x;
    const float* lW = (g == 0) ? lzW : (g == 1) ? lrW : lhW;
    const float* bg = (g == 0) ? bz  : (g == 1) ? br  : bh;
    const float* lb = (g == 0) ? lzb : (g == 1) ? lrb : lhb;
    float s = lb[j];
    for (int mm = 0; mm < 128; ++mm) s += bg[mm] * lW[mm * 128 + j];
    lb2[g * 128 + j] = s;
}

// aggb[i,:] = bf16( dinv[i]^2 * nfb[i,:] + sum_e norm[e] * nfb[src[e],:] )
__global__ __launch_bounds__(256) void agg_feat_kernel(
        const unsigned* __restrict__ nfb32, const float* __restrict__ dinv,
        const int* __restrict__ row_ptr, const int* __restrict__ src_s,
        const float* __restrict__ norm_s, unsigned* __restrict__ aggb32, int n) {
    int t = threadIdx.x & 63;            // column pair
    int grp = threadIdx.x >> 6;
    int i = blockIdx.x * 4 + grp;
    if (i >= n) return;
    float di = dinv[i];
    unsigned uself = nfb32[(size_t)i * 64 + t];
    float a0 = di * di * bflo(uself);
    float a1 = di * di * bfhi(uself);
    int e0 = row_ptr[i], e1 = row_ptr[i + 1];
    for (int e = e0; e < e1; e += 8) {
        unsigned v[8]; float w[8];
#pragma unroll
        for (int u = 0; u < 8; ++u) {
            int ee = e + u;
            bool ok = ee < e1;
            int s = ok ? src_s[ee] : src_s[e0];
            w[u] = ok ? norm_s[ee] : 0.0f;
            v[u] = nfb32[(size_t)s * 64 + t];
        }
#pragma unroll
        for (int u = 0; u < 8; ++u) {
            a0 += w[u] * bflo(v[u]);
            a1 += w[u] * bfhi(v[u]);
        }
    }
    aggb32[(size_t)i * 64 + t] = (unsigned)f2bf(a0) | ((unsigned)f2bf(a1) << 16);
}

// Fused GRU: 64-row tile per block, 4 waves; wave w owns a 32-col slice and
// ALL 64 rows. Per phase: 16 independent B-loads into REGISTERS (one latency
// round), then 32 LDS A-reads + 64 MFMAs. hq goes to a 3rd LDS buffer.
__global__ __launch_bounds__(256) void gru_fused_kernel(
        const ushort* __restrict__ aggb, const ushort* __restrict__ h0b,
        const ushort* __restrict__ BT, const float* __restrict__ lb2,
        float* __restrict__ hout, int n) {
    __shared__ ushort Aag[64][136];   // agg tile (pad 8 -> 2-way alias, free)
    __shared__ ushort Ah0[64][136];   // h0 tile (bf16)
    __shared__ ushort Ahq[64][136];   // h0*r tile
    int t = threadIdx.x;
    int i0 = blockIdx.x * 64;

    for (int c = t; c < 1024; c += 256) {
        int row = c >> 4, c8 = c & 15;
        size_t gp = (size_t)(i0 + row) * HD + c8 * 8;
        *(short8*)&Aag[row][c8 * 8] = *(const short8*)(aggb + gp);
        *(short8*)&Ah0[row][c8 * 8] = *(const short8*)(h0b + gp);
    }
    __syncthreads();

    int w = t >> 6, lane = t & 63;
    int rlo = lane & 15, koff = (lane >> 4) * 8, rbase = (lane >> 4) * 4;
    int c0 = w * 32;                    // wave's column base within gate

    const f32x4 zero4 = {0.f, 0.f, 0.f, 0.f};
    short8 bfr[2][8];
    f32x4 acc[4][2];
    float zv[4][2][4];

    // ================= phase Z (gate 0) =================
#pragma unroll
    for (int cf = 0; cf < 2; ++cf)
#pragma unroll
        for (int ks = 0; ks < 8; ++ks)
            bfr[cf][ks] = *(const short8*)(BT + (size_t)(c0 + cf * 16 + rlo) * 256
                                           + ks * 32 + koff);
#pragma unroll
    for (int rf = 0; rf < 4; ++rf) { acc[rf][0] = zero4; acc[rf][1] = zero4; }
#pragma unroll
    for (int rf = 0; rf < 4; ++rf)
#pragma unroll
        for (int ks = 0; ks < 8; ++ks) {
            short8 af = (ks < 4)
                ? *(const short8*)&Aag[rf * 16 + rlo][ks * 32 + koff]
                : *(const short8*)&Ah0[rf * 16 + rlo][(ks - 4) * 32 + koff];
            acc[rf][0] = __builtin_amdgcn_mfma_f32_16x16x32_bf16(af, bfr[0][ks], acc[rf][0], 0, 0, 0);
            acc[rf][1] = __builtin_amdgcn_mfma_f32_16x16x32_bf16(af, bfr[1][ks], acc[rf][1], 0, 0, 0);
        }
#pragma unroll
    for (int rf = 0; rf < 4; ++rf)
#pragma unroll
        for (int cf = 0; cf < 2; ++cf) {
            float bv = lb2[c0 + cf * 16 + rlo];
#pragma unroll
            for (int i = 0; i < 4; ++i)
                zv[rf][cf][i] = fast_sigmoid(acc[rf][cf][i] + bv);
        }

    // ================= phase R (gate 1) =================
#pragma unroll
    for (int cf = 0; cf < 2; ++cf)
#pragma unroll
        for (int ks = 0; ks < 8; ++ks)
            bfr[cf][ks] = *(const short8*)(BT + (size_t)(128 + c0 + cf * 16 + rlo) * 256
                                           + ks * 32 + koff);
#pragma unroll
    for (int rf = 0; rf < 4; ++rf) { acc[rf][0] = zero4; acc[rf][1] = zero4; }
#pragma unroll
    for (int rf = 0; rf < 4; ++rf)
#pragma unroll
        for (int ks = 0; ks < 8; ++ks) {
            short8 af = (ks < 4)
                ? *(const short8*)&Aag[rf * 16 + rlo][ks * 32 + koff]
                : *(const short8*)&Ah0[rf * 16 + rlo][(ks - 4) * 32 + koff];
            acc[rf][0] = __builtin_amdgcn_mfma_f32_16x16x32_bf16(af, bfr[0][ks], acc[rf][0], 0, 0, 0);
            acc[rf][1] = __builtin_amdgcn_mfma_f32_16x16x32_bf16(af, bfr[1][ks], acc[rf][1], 0, 0, 0);
        }
#pragma unroll
    for (int rf = 0; rf < 4; ++rf)
#pragma unroll
        for (int cf = 0; cf < 2; ++cf) {
            int lc = c0 + cf * 16 + rlo;
            float bv = lb2[128 + lc];
#pragma unroll
            for (int i = 0; i < 4; ++i) {
                int row = rf * 16 + rbase + i;
                float r = fast_sigmoid(acc[rf][cf][i] + bv);
                Ahq[row][lc] = f2bf(r * bf2f(Ah0[row][lc]));
            }
        }
    __syncthreads();   // hq visible to all waves

    // ================= phase HT (gate 2): A = [agg | hq] =================
#pragma unroll
    for (int cf = 0; cf < 2; ++cf)
#pragma unroll
        for (int ks = 0; ks < 8; ++ks)
            bfr[cf][ks] = *(const short8*)(BT + (size_t)(256 + c0 + cf * 16 + rlo) * 256
                                           + ks * 32 + koff);
#pragma unroll
    for (int rf = 0; rf < 4; ++rf) { acc[rf][0] = zero4; acc[rf][1] = zero4; }
#pragma unroll
    for (int rf = 0; rf < 4; ++rf)
#pragma unroll
        for (int ks = 0; ks < 8; ++ks) {
            short8 af = (ks < 4)
                ? *(const short8*)&Aag[rf * 16 + rlo][ks * 32 + koff]
                : *(const short8*)&Ahq[rf * 16 + rlo][(ks - 4) * 32 + koff];
            acc[rf][0] = __builtin_amdgcn_mfma_f32_16x16x32_bf16(af, bfr[0][ks], acc[rf][0], 0, 0, 0);
            acc[rf][1] = __builtin_amdgcn_mfma_f32_16x16x32_bf16(af, bfr[1][ks], acc[rf][1], 0, 0, 0);
        }
#pragma unroll
    for (int rf = 0; rf < 4; ++rf)
#pragma unroll
        for (int cf = 0; cf < 2; ++cf) {
            int lc = c0 + cf * 16 + rlo;
            float bv = lb2[256 + lc];
#pragma unroll
            for (int i = 0; i < 4; ++i) {
                int row = rf * 16 + rbase + i;
                int grow = i0 + row;
                if (grow < n) {
                    float ht = fast_tanh(acc[rf][cf][i] + bv);
                    float z = zv[rf][cf][i];
                    float h0v = bf2f(Ah0[row][lc]);
                    hout[(size_t)grow * HD + lc] = z * h0v + (1.0f - z) * ht;
                }
            }
        }
}

__global__ __launch_bounds__(128) void pool_kernel(
        const float* __restrict__ hout, const int* __restrict__ nids,
        float* pooled, int U) {
    int t = threadIdx.x;
    float pa = 0.0f;
    for (int u = blockIdx.x; u < U; u += gridDim.x) {
        int nid = nids[u];
        pa += fmaxf(hout[(size_t)nid * HD + t], 0.0f);
    }
    atomicAdd(&pooled[t], pa);
}

__global__ __launch_bounds__(128) void decoder_kernel(
        const float* __restrict__ pooled, float invU,
        const float* __restrict__ linW, const float* __restrict__ linb,
        const float* __restrict__ dnW, const float* __restrict__ dnb,
        const float* __restrict__ outW, const float* __restrict__ outb,
        float* pred, int C) {
    __shared__ float sh[HD];
    int t = threadIdx.x;
    sh[t] = pooled[t] * invU;
    __syncthreads();
    float v = linb[t];
    for (int k = 0; k < HD; ++k) v += sh[k] * linW[k * HD + t];
    __syncthreads();
    sh[t] = v;
    __syncthreads();
    float d = dnb[t];
    for (int k = 0; k < HD; ++k) d += sh[k] * dnW[k * HD + t];
    d = fmaxf(d, 0.0f);
    __syncthreads();
    sh[t] = d;
    __syncthreads();
    if (t < C) {
        float p = outb[t];
        for (int k = 0; k < HD; ++k) p += sh[k] * outW[k * C + t];
        pred[t] = 1.0f / (1.0f + expf(-p));
    }
}

extern "C" void kernel_launch(void* const* d_in, const int* in_sizes, int n_in,
                              void* d_out, int out_size, void* d_ws, size_t ws_size,
                              hipStream_t stream) {
    const float* node_feat = (const float*)d_in[0];
    const float* edge_w    = (const float*)d_in[1];
    const float* h0        = (const float*)d_in[2];
    const float* Wz  = (const float*)d_in[3];  const float* bz  = (const float*)d_in[4];
    const float* Wr  = (const float*)d_in[5];  const float* br  = (const float*)d_in[6];
    const float* Wh  = (const float*)d_in[7];  const float* bh  = (const float*)d_in[8];
    const float* lzW = (const float*)d_in[9];  const float* lzb = (const float*)d_in[10];
    const float* lrW = (const float*)d_in[11]; const float* lrb = (const float*)d_in[12];
    const float* lhW = (const float*)d_in[13]; const float* lhb = (const float*)d_in[14];
    const float* linW= (const float*)d_in[15]; const float* linb= (const float*)d_in[16];
    const float* dnW = (const float*)d_in[17]; const float* dnb = (const float*)d_in[18];
    const float* outW= (const float*)d_in[19]; const float* outb= (const float*)d_in[20];
    const int* src  = (const int*)d_in[21];
    const int* dst  = (const int*)d_in[22];
    const int* nids = (const int*)d_in[23];

    const int N = in_sizes[2] / HD;
    const int E = in_sizes[1];
    const int U = in_sizes[23];
    const int C = in_sizes[20];
    const int NP = (N + 127) & ~127;    // row-padded
    const int NB1K = (N + 1023) / 1024; // scan blocks

    float* out  = (float*)d_out;
    float* pred = out;          // [C]
    float* hout = out + C;      // [N,H]

    // workspace layout (16B-aligned chunks)
    char* p = (char*)d_ws;
    auto alloc = [&](size_t bytes) { char* r = p; p += (bytes + 15) & ~(size_t)15; return r; };
    float* deg    = (float*)alloc((size_t)N * 4);
    float* dinv   = (float*)alloc((size_t)N * 4);
    float* norm_s = (float*)alloc((size_t)E * 4);
    float* pooled = (float*)alloc(HD * 4);
    int*   counts = (int*)alloc((size_t)N * 4);
    int*   row_ptr= (int*)alloc((size_t)(N + 1) * 4);
    int*   cursor = (int*)alloc((size_t)N * 4);
    int*   src_s  = (int*)alloc((size_t)E * 4);
    int*   bsums  = (int*)alloc((size_t)1024 * 4);
    ushort* nfb   = (ushort*)alloc((size_t)NP * HD * 2);
    ushort* aggb  = (ushort*)alloc((size_t)NP * HD * 2);
    ushort* h0b   = (ushort*)alloc((size_t)NP * HD * 2);
    ushort* BT    = (ushort*)alloc((size_t)3 * 128 * 256 * 2);
    float* lb2    = (float*)alloc(384 * 4);

    hipMemsetAsync(counts, 0, (size_t)N * sizeof(int), stream);
    hipMemsetAsync(pooled, 0, HD * sizeof(float), stream);

    int prep_items = N * (HD / 8);
    prep_kernel<<<(prep_items + 255) / 256, 256, 0, stream>>>(node_feat, h0, nfb, h0b, deg, N);
    edge_accum_kernel<<<(E + 255) / 256, 256, 0, stream>>>(dst, edge_w, deg, counts, E);
    dinv_kernel<<<(N + 255) / 256, 256, 0, stream>>>(deg, dinv, N);
    scan_partial_kernel<<<NB1K, 256, 0, stream>>>(counts, bsums, N);
    scan_bsums_kernel<<<1, 1024, 0, stream>>>(bsums, row_ptr + N, NB1K);
    scan_final_kernel<<<NB1K, 256, 0, stream>>>(counts, bsums, row_ptr, cursor, N);
    fill_kernel<<<(E + 255) / 256, 256, 0, stream>>>(src, dst, edge_w, dinv, cursor,
                                                     src_s, norm_s, E);
    dim3 fg(3, 16);
    fuse_weights_kernel<<<fg, 256, 0, stream>>>(Wz, Wr, Wh, lzW, lrW, lhW, BT);
    lb2_kernel<<<3, 128, 0, stream>>>(lzW, lrW, lhW, bz, br, bh, lzb, lrb, lhb, lb2);
    agg_feat_kernel<<<(N + 3) / 4, 256, 0, stream>>>(
        (const unsigned*)nfb, dinv, row_ptr, src_s, norm_s, (unsigned*)aggb, N);
    gru_fused_kernel<<<NP / 64, 256, 0, stream>>>(aggb, h0b, BT, lb2, hout, N);
    pool_kernel<<<512, 128, 0, stream>>>(hout, nids, pooled, U);
    decoder_kernel<<<1, 128, 0, stream>>>(pooled, 1.0f / (float)U,
                                          linW, linb, dnW, dnb, outW, outb, pred, C);
}

// Round 9
// 317.760 us; speedup vs baseline: 1.6094x; 1.0243x over previous
//
#include <hip/hip_runtime.h>
#include <math.h>

// TGCN: bf16 feature-space GCN aggregation (fp32 accum) -> single fused GRU
// kernel (z,r,hq,ht in one pass; B-slice in REGISTERS per wave, A in LDS).
// CSR-by-dst via hierarchical scan. Degree/count histogram uses 8-way
// XCD-local replication to kill cross-XCD atomic line ping-pong.

#define HD 128
#define NREP 8

typedef __attribute__((ext_vector_type(8))) short short8;
typedef __attribute__((ext_vector_type(4))) float f32x4;

__device__ __forceinline__ ushort f2bf(float f) {
    union { float f; unsigned u; } v; v.f = f;
    unsigned r = (v.u + 0x7FFFu + ((v.u >> 16) & 1u)) >> 16;
    return (ushort)r;
}
__device__ __forceinline__ float bf2f(ushort h) {
    union { unsigned u; float f; } v; v.u = ((unsigned)h) << 16;
    return v.f;
}
__device__ __forceinline__ float bflo(unsigned u) {
    union { unsigned u; float f; } v; v.u = u << 16; return v.f;
}
__device__ __forceinline__ float bfhi(unsigned u) {
    union { unsigned u; float f; } v; v.u = u & 0xFFFF0000u; return v.f;
}
__device__ __forceinline__ float fast_sigmoid(float x) {
    return 1.0f / (1.0f + __expf(-x));
}
__device__ __forceinline__ float fast_tanh(float x) {
    float e = __expf(-2.0f * fabsf(x));
    float m = (1.0f - e) / (1.0f + e);
    return copysignf(m, x);
}

// nf -> bf16, h0 -> bf16 (vectorized)
__global__ void prep_kernel(const float* __restrict__ nf, const float* __restrict__ h0,
                            ushort* __restrict__ nfb, ushort* __restrict__ h0b, int n) {
    int idx = blockIdx.x * 256 + threadIdx.x;
    int total8 = n * (HD / 8);
    if (idx < total8) {
        const float4* p = (const float4*)(nf + (size_t)idx * 8);
        float4 x = p[0], y = p[1];
        short8 o;
        o[0] = (short)f2bf(x.x); o[1] = (short)f2bf(x.y);
        o[2] = (short)f2bf(x.z); o[3] = (short)f2bf(x.w);
        o[4] = (short)f2bf(y.x); o[5] = (short)f2bf(y.y);
        o[6] = (short)f2bf(y.z); o[7] = (short)f2bf(y.w);
        *(short8*)(nfb + (size_t)idx * 8) = o;
        const float4* q = (const float4*)(h0 + (size_t)idx * 8);
        float4 a = q[0], b = q[1];
        short8 o2;
        o2[0] = (short)f2bf(a.x); o2[1] = (short)f2bf(a.y);
        o2[2] = (short)f2bf(a.z); o2[3] = (short)f2bf(a.w);
        o2[4] = (short)f2bf(b.x); o2[5] = (short)f2bf(b.y);
        o2[6] = (short)f2bf(b.z); o2[7] = (short)f2bf(b.w);
        *(short8*)(h0b + (size_t)idx * 8) = o2;
    }
}

// Replicated histogram: counts_r[rep][d]++, deg_r[rep][d]+=w; rep = blockIdx&7
// (consecutive blocks round-robin XCDs -> replica lines stay XCD-local).
__global__ __launch_bounds__(256) void hist_kernel(
        const int* __restrict__ dst, const float* __restrict__ w,
        int* __restrict__ counts_r, float* __restrict__ deg_r, int N, int E) {
    int rep = blockIdx.x & (NREP - 1);
    int* cr = counts_r + (size_t)rep * N;
    float* dr = deg_r + (size_t)rep * N;
    int base = blockIdx.x * 1024 + threadIdx.x * 4;
#pragma unroll
    for (int u = 0; u < 4; ++u) {
        int e = base + u;
        if (e < E) {
            int d = dst[e];
            atomicAdd(&cr[d], 1);
            atomicAdd(&dr[d], w[e]);
        }
    }
}

// counts = sum_r counts_r;  dinv = rsqrt(1 + sum_r deg_r)
__global__ __launch_bounds__(256) void reduce_hist_kernel(
        const int* __restrict__ counts_r, const float* __restrict__ deg_r,
        int* __restrict__ counts, float* __restrict__ dinv, int N) {
    int i = blockIdx.x * 256 + threadIdx.x;
    if (i >= N) return;
    int c = 0;
    float d = 1.0f;
#pragma unroll
    for (int r = 0; r < NREP; ++r) {
        c += counts_r[(size_t)r * N + i];
        d += deg_r[(size_t)r * N + i];
    }
    counts[i] = c;
    dinv[i] = (d > 0.0f) ? rsqrtf(d) : 0.0f;
}

// ---- hierarchical scan: partial sums (1024 elems / 256-thr block) ----
__global__ __launch_bounds__(256) void scan_partial_kernel(
        const int* __restrict__ counts, int* __restrict__ bsums, int n) {
    __shared__ int ws[4];
    int b = blockIdx.x, t = threadIdx.x;
    int idx = b * 1024 + t * 4;
    int4 v = {0, 0, 0, 0};
    if (idx + 3 < n) v = *(const int4*)(counts + idx);
    else {
        if (idx < n) v.x = counts[idx];
        if (idx + 1 < n) v.y = counts[idx + 1];
        if (idx + 2 < n) v.z = counts[idx + 2];
        if (idx + 3 < n) v.w = counts[idx + 3];
    }
    int s = v.x + v.y + v.z + v.w;
    for (int off = 1; off < 64; off <<= 1) s += __shfl_xor(s, off, 64);
    if ((t & 63) == 0) ws[t >> 6] = s;
    __syncthreads();
    if (t == 0) bsums[b] = ws[0] + ws[1] + ws[2] + ws[3];
}

// scan of nb (<=1024) block sums -> exclusive; writes row_ptr[n]
__global__ __launch_bounds__(1024) void scan_bsums_kernel(
        int* __restrict__ bsums, int* __restrict__ rp_total, int nb) {
    __shared__ int ws[16];
    int t = threadIdx.x;
    int v = (t < nb) ? bsums[t] : 0;
    int lane = t & 63, wid = t >> 6;
    int x = v;
    for (int off = 1; off < 64; off <<= 1) {
        int y = __shfl_up(x, off, 64);
        if (lane >= off) x += y;
    }
    if (lane == 63) ws[wid] = x;
    __syncthreads();
    if (wid == 0) {
        int s = (lane < 16) ? ws[lane] : 0;
        for (int off = 1; off < 16; off <<= 1) {
            int y = __shfl_up(s, off, 64);
            if (lane >= off) s += y;
        }
        if (lane < 16) ws[lane] = s;
    }
    __syncthreads();
    int excl = x - v + ((wid == 0) ? 0 : ws[wid - 1]);
    if (t < nb) bsums[t] = excl;
    if (t == nb - 1) *rp_total = excl + v;
}

// final: per-block local scan + block offset -> row_ptr, cursor
__global__ __launch_bounds__(256) void scan_final_kernel(
        const int* __restrict__ counts, const int* __restrict__ bsums,
        int* __restrict__ row_ptr, int* __restrict__ cursor, int n) {
    __shared__ int ws[4];
    int b = blockIdx.x, t = threadIdx.x;
    int idx = b * 1024 + t * 4;
    int4 v = {0, 0, 0, 0};
    if (idx + 3 < n) v = *(const int4*)(counts + idx);
    else {
        if (idx < n) v.x = counts[idx];
        if (idx + 1 < n) v.y = counts[idx + 1];
        if (idx + 2 < n) v.z = counts[idx + 2];
        if (idx + 3 < n) v.w = counts[idx + 3];
    }
    int s = v.x + v.y + v.z + v.w;
    int lane = t & 63, wid = t >> 6;
    int x = s;
    for (int off = 1; off < 64; off <<= 1) {
        int y = __shfl_up(x, off, 64);
        if (lane >= off) x += y;
    }
    if (lane == 63) ws[wid] = x;
    __syncthreads();
    int woff = 0;
    for (int wv = 0; wv < wid; ++wv) woff += ws[wv];
    int run = bsums[b] + woff + x - s;
    int4 rp;
    rp.x = run; rp.y = run + v.x; rp.z = rp.y + v.y; rp.w = rp.z + v.z;
    if (idx + 3 < n) {
        *(int4*)(row_ptr + idx) = rp;
        *(int4*)(cursor + idx) = rp;
    } else {
        if (idx < n) { row_ptr[idx] = rp.x; cursor[idx] = rp.x; }
        if (idx + 1 < n) { row_ptr[idx + 1] = rp.y; cursor[idx + 1] = rp.y; }
        if (idx + 2 < n) { row_ptr[idx + 2] = rp.z; cursor[idx + 2] = rp.z; }
        if (idx + 3 < n) { row_ptr[idx + 3] = rp.w; cursor[idx + 3] = rp.w; }
    }
}

__global__ void fill_kernel(const int* __restrict__ src, const int* __restrict__ dst,
                            const float* __restrict__ w, const float* __restrict__ dinv,
                            int* cursor, int* src_s, float* norm_s, int E) {
    int e = blockIdx.x * blockDim.x + threadIdx.x;
    if (e < E) {
        int s = src[e], d = dst[e];
        int p = atomicAdd(&cursor[d], 1);
        src_s[p] = s;
        norm_s[p] = dinv[s] * w[e] * dinv[d];
    }
}

// Fused-weight build, parallel+coalesced. grid (3,16), 256 thr.
__global__ __launch_bounds__(256) void fuse_weights_kernel(
        const float* __restrict__ Wz, const float* __restrict__ Wr,
        const float* __restrict__ Wh,
        const float* __restrict__ lzW, const float* __restrict__ lrW,
        const float* __restrict__ lhW,
        ushort* __restrict__ BT) {
    int g = blockIdx.x, kt = blockIdx.y;
    const float* W  = (g == 0) ? Wz  : (g == 1) ? Wr  : Wh;
    const float* lW = (g == 0) ? lzW : (g == 1) ? lrW : lhW;
    int t = threadIdx.x;
    int j = t & 127, kh = t >> 7;          // kh in {0,1}
    int k0 = kt * 8 + kh * 4;
    float m0 = 0.f, m1 = 0.f, m2 = 0.f, m3 = 0.f;
    for (int mm = 0; mm < 128; ++mm) {
        float lv = lW[mm * 128 + j];       // coalesced across j
        m0 += W[(k0 + 0) * 128 + mm] * lv; // wave-uniform -> broadcast
        m1 += W[(k0 + 1) * 128 + mm] * lv;
        m2 += W[(k0 + 2) * 128 + mm] * lv;
        m3 += W[(k0 + 3) * 128 + mm] * lv;
    }
    ushort* dstc = BT + ((size_t)g * 128 + j) * 256;
    dstc[k0 + 0] = f2bf(m0); dstc[k0 + 1] = f2bf(m1);
    dstc[k0 + 2] = f2bf(m2); dstc[k0 + 3] = f2bf(m3);
#pragma unroll
    for (int u = 0; u < 4; ++u) {
        int mm = k0 + u;
        dstc[128 + mm] = f2bf(lW[(128 + mm) * 128 + j]);
    }
}

// lb2[g][j] = lgb[j] + sum_m bg[m]*lgW_top[m][j]
__global__ __launch_bounds__(128) void lb2_kernel(
        const float* __restrict__ lzW, const float* __restrict__ lrW,
        const float* __restrict__ lhW,
        const float* __restrict__ bz, const float* __restrict__ br,
        const float* __restrict__ bh,
        const float* __restrict__ lzb, const float* __restrict__ lrb,
        const float* __restrict__ lhb,
        float* __restrict__ lb2) {
    int g = blockIdx.x, j = threadIdx.x;
    const float* lW = (g == 0) ? lzW : (g == 1) ? lrW : lhW;
    const float* bg = (g == 0) ? bz  : (g == 1) ? br  : bh;
    const float* lb = (g == 0) ? lzb : (g == 1) ? lrb : lhb;
    float s = lb[j];
    for (int mm = 0; mm < 128; ++mm) s += bg[mm] * lW[mm * 128 + j];
    lb2[g * 128 + j] = s;
}

// aggb[i,:] = bf16( dinv[i]^2 * nfb[i,:] + sum_e norm[e] * nfb[src[e],:] )
__global__ __launch_bounds__(256) void agg_feat_kernel(
        const unsigned* __restrict__ nfb32, const float* __restrict__ dinv,
        const int* __restrict__ row_ptr, const int* __restrict__ src_s,
        const float* __restrict__ norm_s, unsigned* __restrict__ aggb32, int n) {
    int t = threadIdx.x & 63;            // column pair
    int grp = threadIdx.x >> 6;
    int i = blockIdx.x * 4 + grp;
    if (i >= n) return;
    float di = dinv[i];
    unsigned uself = nfb32[(size_t)i * 64 + t];
    float a0 = di * di * bflo(uself);
    float a1 = di * di * bfhi(uself);
    int e0 = row_ptr[i], e1 = row_ptr[i + 1];
    for (int e = e0; e < e1; e += 8) {
        unsigned v[8]; float w[8];
#pragma unroll
        for (int u = 0; u < 8; ++u) {
            int ee = e + u;
            bool ok = ee < e1;
            int s = ok ? src_s[ee] : src_s[e0];
            w[u] = ok ? norm_s[ee] : 0.0f;
            v[u] = nfb32[(size_t)s * 64 + t];
        }
#pragma unroll
        for (int u = 0; u < 8; ++u) {
            a0 += w[u] * bflo(v[u]);
            a1 += w[u] * bfhi(v[u]);
        }
    }
    aggb32[(size_t)i * 64 + t] = (unsigned)f2bf(a0) | ((unsigned)f2bf(a1) << 16);
}

// Fused GRU: 64-row tile per block, 4 waves; wave w owns a 32-col slice and
// ALL 64 rows. Per phase: 16 independent B-loads into REGISTERS (one latency
// round), then 32 LDS A-reads + 64 MFMAs. hq goes to a 3rd LDS buffer.
__global__ __launch_bounds__(256) void gru_fused_kernel(
        const ushort* __restrict__ aggb, const ushort* __restrict__ h0b,
        const ushort* __restrict__ BT, const float* __restrict__ lb2,
        float* __restrict__ hout, int n) {
    __shared__ ushort Aag[64][136];   // agg tile (pad 8 -> 2-way alias, free)
    __shared__ ushort Ah0[64][136];   // h0 tile (bf16)
    __shared__ ushort Ahq[64][136];   // h0*r tile
    int t = threadIdx.x;
    int i0 = blockIdx.x * 64;

    for (int c = t; c < 1024; c += 256) {
        int row = c >> 4, c8 = c & 15;
        size_t gp = (size_t)(i0 + row) * HD + c8 * 8;
        *(short8*)&Aag[row][c8 * 8] = *(const short8*)(aggb + gp);
        *(short8*)&Ah0[row][c8 * 8] = *(const short8*)(h0b + gp);
    }
    __syncthreads();

    int w = t >> 6, lane = t & 63;
    int rlo = lane & 15, koff = (lane >> 4) * 8, rbase = (lane >> 4) * 4;
    int c0 = w * 32;                    // wave's column base within gate

    const f32x4 zero4 = {0.f, 0.f, 0.f, 0.f};
    short8 bfr[2][8];
    f32x4 acc[4][2];
    float zv[4][2][4];

    // ================= phase Z (gate 0) =================
#pragma unroll
    for (int cf = 0; cf < 2; ++cf)
#pragma unroll
        for (int ks = 0; ks < 8; ++ks)
            bfr[cf][ks] = *(const short8*)(BT + (size_t)(c0 + cf * 16 + rlo) * 256
                                           + ks * 32 + koff);
#pragma unroll
    for (int rf = 0; rf < 4; ++rf) { acc[rf][0] = zero4; acc[rf][1] = zero4; }
#pragma unroll
    for (int rf = 0; rf < 4; ++rf)
#pragma unroll
        for (int ks = 0; ks < 8; ++ks) {
            short8 af = (ks < 4)
                ? *(const short8*)&Aag[rf * 16 + rlo][ks * 32 + koff]
                : *(const short8*)&Ah0[rf * 16 + rlo][(ks - 4) * 32 + koff];
            acc[rf][0] = __builtin_amdgcn_mfma_f32_16x16x32_bf16(af, bfr[0][ks], acc[rf][0], 0, 0, 0);
            acc[rf][1] = __builtin_amdgcn_mfma_f32_16x16x32_bf16(af, bfr[1][ks], acc[rf][1], 0, 0, 0);
        }
#pragma unroll
    for (int rf = 0; rf < 4; ++rf)
#pragma unroll
        for (int cf = 0; cf < 2; ++cf) {
            float bv = lb2[c0 + cf * 16 + rlo];
#pragma unroll
            for (int i = 0; i < 4; ++i)
                zv[rf][cf][i] = fast_sigmoid(acc[rf][cf][i] + bv);
        }

    // ================= phase R (gate 1) =================
#pragma unroll
    for (int cf = 0; cf < 2; ++cf)
#pragma unroll
        for (int ks = 0; ks < 8; ++ks)
            bfr[cf][ks] = *(const short8*)(BT + (size_t)(128 + c0 + cf * 16 + rlo) * 256
                                           + ks * 32 + koff);
#pragma unroll
    for (int rf = 0; rf < 4; ++rf) { acc[rf][0] = zero4; acc[rf][1] = zero4; }
#pragma unroll
    for (int rf = 0; rf < 4; ++rf)
#pragma unroll
        for (int ks = 0; ks < 8; ++ks) {
            short8 af = (ks < 4)
                ? *(const short8*)&Aag[rf * 16 + rlo][ks * 32 + koff]
                : *(const short8*)&Ah0[rf * 16 + rlo][(ks - 4) * 32 + koff];
            acc[rf][0] = __builtin_amdgcn_mfma_f32_16x16x32_bf16(af, bfr[0][ks], acc[rf][0], 0, 0, 0);
            acc[rf][1] = __builtin_amdgcn_mfma_f32_16x16x32_bf16(af, bfr[1][ks], acc[rf][1], 0, 0, 0);
        }
#pragma unroll
    for (int rf = 0; rf < 4; ++rf)
#pragma unroll
        for (int cf = 0; cf < 2; ++cf) {
            int lc = c0 + cf * 16 + rlo;
            float bv = lb2[128 + lc];
#pragma unroll
            for (int i = 0; i < 4; ++i) {
                int row = rf * 16 + rbase + i;
                float r = fast_sigmoid(acc[rf][cf][i] + bv);
                Ahq[row][lc] = f2bf(r * bf2f(Ah0[row][lc]));
            }
        }
    __syncthreads();   // hq visible to all waves

    // ================= phase HT (gate 2): A = [agg | hq] =================
#pragma unroll
    for (int cf = 0; cf < 2; ++cf)
#pragma unroll
        for (int ks = 0; ks < 8; ++ks)
            bfr[cf][ks] = *(const short8*)(BT + (size_t)(256 + c0 + cf * 16 + rlo) * 256
                                           + ks * 32 + koff);
#pragma unroll
    for (int rf = 0; rf < 4; ++rf) { acc[rf][0] = zero4; acc[rf][1] = zero4; }
#pragma unroll
    for (int rf = 0; rf < 4; ++rf)
#pragma unroll
        for (int ks = 0; ks < 8; ++ks) {
            short8 af = (ks < 4)
                ? *(const short8*)&Aag[rf * 16 + rlo][ks * 32 + koff]
                : *(const short8*)&Ahq[rf * 16 + rlo][(ks - 4) * 32 + koff];
            acc[rf][0] = __builtin_amdgcn_mfma_f32_16x16x32_bf16(af, bfr[0][ks], acc[rf][0], 0, 0, 0);
            acc[rf][1] = __builtin_amdgcn_mfma_f32_16x16x32_bf16(af, bfr[1][ks], acc[rf][1], 0, 0, 0);
        }
#pragma unroll
    for (int rf = 0; rf < 4; ++rf)
#pragma unroll
        for (int cf = 0; cf < 2; ++cf) {
            int lc = c0 + cf * 16 + rlo;
            float bv = lb2[256 + lc];
#pragma unroll
            for (int i = 0; i < 4; ++i) {
                int row = rf * 16 + rbase + i;
                int grow = i0 + row;
                if (grow < n) {
                    float ht = fast_tanh(acc[rf][cf][i] + bv);
                    float z = zv[rf][cf][i];
                    float h0v = bf2f(Ah0[row][lc]);
                    hout[(size_t)grow * HD + lc] = z * h0v + (1.0f - z) * ht;
                }
            }
        }
}

__global__ __launch_bounds__(128) void pool_kernel(
        const float* __restrict__ hout, const int* __restrict__ nids,
        float* pooled, int U) {
    int t = threadIdx.x;
    float pa = 0.0f;
    for (int u = blockIdx.x; u < U; u += gridDim.x) {
        int nid = nids[u];
        pa += fmaxf(hout[(size_t)nid * HD + t], 0.0f);
    }
    atomicAdd(&pooled[t], pa);
}

__global__ __launch_bounds__(128) void decoder_kernel(
        const float* __restrict__ pooled, float invU,
        const float* __restrict__ linW, const float* __restrict__ linb,
        const float* __restrict__ dnW, const float* __restrict__ dnb,
        const float* __restrict__ outW, const float* __restrict__ outb,
        float* pred, int C) {
    __shared__ float sh[HD];
    int t = threadIdx.x;
    sh[t] = pooled[t] * invU;
    __syncthreads();
    float v = linb[t];
    for (int k = 0; k < HD; ++k) v += sh[k] * linW[k * HD + t];
    __syncthreads();
    sh[t] = v;
    __syncthreads();
    float d = dnb[t];
    for (int k = 0; k < HD; ++k) d += sh[k] * dnW[k * HD + t];
    d = fmaxf(d, 0.0f);
    __syncthreads();
    sh[t] = d;
    __syncthreads();
    if (t < C) {
        float p = outb[t];
        for (int k = 0; k < HD; ++k) p += sh[k] * outW[k * C + t];
        pred[t] = 1.0f / (1.0f + expf(-p));
    }
}

extern "C" void kernel_launch(void* const* d_in, const int* in_sizes, int n_in,
                              void* d_out, int out_size, void* d_ws, size_t ws_size,
                              hipStream_t stream) {
    const float* node_feat = (const float*)d_in[0];
    const float* edge_w    = (const float*)d_in[1];
    const float* h0        = (const float*)d_in[2];
    const float* Wz  = (const float*)d_in[3];  const float* bz  = (const float*)d_in[4];
    const float* Wr  = (const float*)d_in[5];  const float* br  = (const float*)d_in[6];
    const float* Wh  = (const float*)d_in[7];  const float* bh  = (const float*)d_in[8];
    const float* lzW = (const float*)d_in[9];  const float* lzb = (const float*)d_in[10];
    const float* lrW = (const float*)d_in[11]; const float* lrb = (const float*)d_in[12];
    const float* lhW = (const float*)d_in[13]; const float* lhb = (const float*)d_in[14];
    const float* linW= (const float*)d_in[15]; const float* linb= (const float*)d_in[16];
    const float* dnW = (const float*)d_in[17]; const float* dnb = (const float*)d_in[18];
    const float* outW= (const float*)d_in[19]; const float* outb= (const float*)d_in[20];
    const int* src  = (const int*)d_in[21];
    const int* dst  = (const int*)d_in[22];
    const int* nids = (const int*)d_in[23];

    const int N = in_sizes[2] / HD;
    const int E = in_sizes[1];
    const int U = in_sizes[23];
    const int C = in_sizes[20];
    const int NP = (N + 127) & ~127;    // row-padded
    const int NB1K = (N + 1023) / 1024; // scan blocks

    float* out  = (float*)d_out;
    float* pred = out;          // [C]
    float* hout = out + C;      // [N,H]

    // workspace layout (16B-aligned chunks)
    char* p = (char*)d_ws;
    auto alloc = [&](size_t bytes) { char* r = p; p += (bytes + 15) & ~(size_t)15; return r; };
    float* dinv   = (float*)alloc((size_t)N * 4);
    float* norm_s = (float*)alloc((size_t)E * 4);
    float* pooled = (float*)alloc(HD * 4);
    int*   counts = (int*)alloc((size_t)N * 4);
    int*   row_ptr= (int*)alloc((size_t)(N + 1) * 4);
    int*   cursor = (int*)alloc((size_t)N * 4);
    int*   src_s  = (int*)alloc((size_t)E * 4);
    int*   bsums  = (int*)alloc((size_t)1024 * 4);
    int*   counts_r = (int*)alloc((size_t)NREP * N * 4);
    float* deg_r    = (float*)alloc((size_t)NREP * N * 4);
    ushort* nfb   = (ushort*)alloc((size_t)NP * HD * 2);
    ushort* aggb  = (ushort*)alloc((size_t)NP * HD * 2);
    ushort* h0b   = (ushort*)alloc((size_t)NP * HD * 2);
    ushort* BT    = (ushort*)alloc((size_t)3 * 128 * 256 * 2);
    float* lb2    = (float*)alloc(384 * 4);

    hipMemsetAsync(counts_r, 0, (size_t)NREP * N * 4, stream);
    hipMemsetAsync(deg_r, 0, (size_t)NREP * N * 4, stream);
    hipMemsetAsync(pooled, 0, HD * sizeof(float), stream);

    int prep_items = N * (HD / 8);
    prep_kernel<<<(prep_items + 255) / 256, 256, 0, stream>>>(node_feat, h0, nfb, h0b, N);
    hist_kernel<<<(E + 1023) / 1024, 256, 0, stream>>>(dst, edge_w, counts_r, deg_r, N, E);
    reduce_hist_kernel<<<(N + 255) / 256, 256, 0, stream>>>(counts_r, deg_r, counts, dinv, N);
    scan_partial_kernel<<<NB1K, 256, 0, stream>>>(counts, bsums, N);
    scan_bsums_kernel<<<1, 1024, 0, stream>>>(bsums, row_ptr + N, NB1K);
    scan_final_kernel<<<NB1K, 256, 0, stream>>>(counts, bsums, row_ptr, cursor, N);
    fill_kernel<<<(E + 255) / 256, 256, 0, stream>>>(src, dst, edge_w, dinv, cursor,
                                                     src_s, norm_s, E);
    dim3 fg(3, 16);
    fuse_weights_kernel<<<fg, 256, 0, stream>>>(Wz, Wr, Wh, lzW, lrW, lhW, BT);
    lb2_kernel<<<3, 128, 0, stream>>>(lzW, lrW, lhW, bz, br, bh, lzb, lrb, lhb, lb2);
    agg_feat_kernel<<<(N + 3) / 4, 256, 0, stream>>>(
        (const unsigned*)nfb, dinv, row_ptr, src_s, norm_s, (unsigned*)aggb, N);
    gru_fused_kernel<<<NP / 64, 256, 0, stream>>>(aggb, h0b, BT, lb2, hout, N);
    pool_kernel<<<512, 128, 0, stream>>>(hout, nids, pooled, U);
    decoder_kernel<<<1, 128, 0, stream>>>(pooled, 1.0f / (float)U,
                                          linW, linb, dnW, dnb, outW, outb, pred, C);
}